// Round 6
// baseline (3814.914 us; speedup 1.0000x reference)
//
#include <hip/hip_runtime.h>
#include <hip/hip_bf16.h>
#include <math.h>

typedef float v4f __attribute__((ext_vector_type(4)));
typedef short bf16x8 __attribute__((ext_vector_type(8)));   // 8 bf16 (4 VGPR)
typedef float f32x16 __attribute__((ext_vector_type(16)));

#define BATCH 4
#define NQ 4096
#define NK 4096
#define DIM 256
#define INNER 64
#define NEG_INF (-3.0e38f)

// ---------- K1: out[rows,64] = (X[rows,256] @ W[256,64]) * scale -------------
__global__ __launch_bounds__(256) void proj_kernel(
    const float* __restrict__ X, const float* __restrict__ W,
    float* __restrict__ out, float scale)
{
  __shared__ float xs[64 * 260];
  const int t = threadIdx.x;
  const int row0 = blockIdx.x * 64;

  #pragma unroll
  for (int it = 0; it < 16; ++it) {
    int idx = it * 256 + t;
    int r = idx >> 6, dq = idx & 63;
    v4f v = *reinterpret_cast<const v4f*>(X + (size_t)(row0 + r) * DIM + dq * 4);
    *reinterpret_cast<v4f*>(&xs[r * 260 + dq * 4]) = v;
  }
  __syncthreads();

  const int i0 = (t & 15) * 4;
  const int rg = t >> 4;
  float acc[4][4];
  #pragma unroll
  for (int p = 0; p < 4; ++p)
    #pragma unroll
    for (int i = 0; i < 4; ++i) acc[p][i] = 0.f;

  for (int d0 = 0; d0 < DIM; d0 += 4) {
    v4f w0 = *reinterpret_cast<const v4f*>(W + (d0 + 0) * INNER + i0);
    v4f w1 = *reinterpret_cast<const v4f*>(W + (d0 + 1) * INNER + i0);
    v4f w2 = *reinterpret_cast<const v4f*>(W + (d0 + 2) * INNER + i0);
    v4f w3 = *reinterpret_cast<const v4f*>(W + (d0 + 3) * INNER + i0);
    #pragma unroll
    for (int p = 0; p < 4; ++p) {
      v4f x = *reinterpret_cast<const v4f*>(&xs[(rg + 16 * p) * 260 + d0]);
      #pragma unroll
      for (int i = 0; i < 4; ++i) {
        float bs = x[0] * w0[i];
        bs = fmaf(x[1], w1[i], bs);
        bs = fmaf(x[2], w2[i], bs);
        bs = fmaf(x[3], w3[i], bs);
        acc[p][i] += bs;
      }
    }
  }
  #pragma unroll
  for (int p = 0; p < 4; ++p) {
    v4f o;
    #pragma unroll
    for (int i = 0; i < 4; ++i) o[i] = acc[p][i] * scale;
    *reinterpret_cast<v4f*>(out + (size_t)(row0 + rg + 16 * p) * INNER + i0) = o;
  }
}

// ---------- K1b: f32 -> bf16 (RNE), 8 elems/thread ---------------------------
__global__ __launch_bounds__(256) void tobf16_kernel(
    const float* __restrict__ in, ushort* __restrict__ out)
{
  int i = (blockIdx.x * 256 + threadIdx.x) * 8;
  v4f a = *reinterpret_cast<const v4f*>(in + i);
  v4f b = *reinterpret_cast<const v4f*>(in + i + 4);
  ushort o[8];
  #pragma unroll
  for (int e = 0; e < 4; ++e) {
    __hip_bfloat16 ha = __float2bfloat16(a[e]);
    __hip_bfloat16 hb = __float2bfloat16(b[e]);
    o[e]     = *reinterpret_cast<ushort*>(&ha);
    o[e + 4] = *reinterpret_cast<ushort*>(&hb);
  }
  *reinterpret_cast<bf16x8*>(out + i) = *reinterpret_cast<bf16x8*>(o);
}

// ---------- sorted insert helpers (call only when x > v[last]) ---------------
__device__ __forceinline__ void insert5(float (&v)[5], int (&ix)[5], float x, int xi) {
  bool g0 = x > v[0], g1 = x > v[1], g2 = x > v[2], g3 = x > v[3];
  v[4]  = g3 ? v[3] : x;                 ix[4] = g3 ? ix[3] : xi;
  v[3]  = g3 ? (g2 ? v[2] : x) : v[3];   ix[3] = g3 ? (g2 ? ix[2] : xi) : ix[3];
  v[2]  = g2 ? (g1 ? v[1] : x) : v[2];   ix[2] = g2 ? (g1 ? ix[1] : xi) : ix[2];
  v[1]  = g1 ? (g0 ? v[0] : x) : v[1];   ix[1] = g1 ? (g0 ? ix[0] : xi) : ix[1];
  v[0]  = g0 ? x : v[0];                 ix[0] = g0 ? xi : ix[0];
}

__device__ __forceinline__ void insert8(float (&v)[8], int (&ix)[8], float x, int xi) {
  bool g0 = x > v[0], g1 = x > v[1], g2 = x > v[2], g3 = x > v[3];
  bool g4 = x > v[4], g5 = x > v[5], g6 = x > v[6];
  v[7] = g6 ? v[6] : x;                 ix[7] = g6 ? ix[6] : xi;
  v[6] = g6 ? (g5 ? v[5] : x) : v[6];   ix[6] = g6 ? (g5 ? ix[5] : xi) : ix[6];
  v[5] = g5 ? (g4 ? v[4] : x) : v[5];   ix[5] = g5 ? (g4 ? ix[4] : xi) : ix[5];
  v[4] = g4 ? (g3 ? v[3] : x) : v[4];   ix[4] = g4 ? (g3 ? ix[3] : xi) : ix[4];
  v[3] = g3 ? (g2 ? v[2] : x) : v[3];   ix[3] = g3 ? (g2 ? ix[2] : xi) : ix[3];
  v[2] = g2 ? (g1 ? v[1] : x) : v[2];   ix[2] = g2 ? (g1 ? ix[1] : xi) : ix[2];
  v[1] = g1 ? (g0 ? v[0] : x) : v[1];   ix[1] = g1 ? (g0 ? ix[0] : xi) : ix[1];
  v[0] = g0 ? x : v[0];                 ix[0] = g0 ? xi : ix[0];
}

// ---------- K2: MFMA bf16 filter (top-8) + exact f32 rescore + top-5 ---------
// 512 thr = 8 waves. Block = 32 q-rows; wave qg owns k-cols [qg*512,(qg+1)*512).
// Swapped MFMA: acc = kh_tile(32x16) x qh_tile(16x32) so each lane's 16 acc
// values belong to ONE q-row (col = lane&31). C layout (verified m74/m101):
// krow = (reg&3) + 8*(reg>>2) + 4*(lane>>5). A/B: row|col = lane&31,
// kdim = (lane>>5)*8 + e.
__global__ __launch_bounds__(512, 2) void filter_kernel(
    const ushort* __restrict__ qhb, const ushort* __restrict__ khb,
    const float* __restrict__ qh, const float* __restrict__ kh,
    float* __restrict__ topout)
{
  __shared__ float qhf[32][68];        // f32 q rows for exact rescore
  __shared__ float mrgv[32 * 66];      // [row]*66 + wave*8 + j
  __shared__ int   mrgi[32 * 66];
  __shared__ float candv[32][9];
  __shared__ int   candi[32][9];
  __shared__ float exactv[32][9];

  const int t   = threadIdx.x;
  const int bid = blockIdx.x;
  const int wg  = (bid & 7) * 64 + (bid >> 3);   // XCD swizzle (512 = 8*64)
  const int b   = wg >> 7;
  const int q0  = (wg & 127) * 32;
  const int qg  = t >> 6;                        // wave 0..7
  const int kg  = t & 63;                        // lane
  const int ln  = kg & 31;
  const int hi  = kg >> 5;

  // stage f32 q rows for rescore
  {
    int row = t >> 4, c4 = (t & 15) * 4;
    v4f v = *reinterpret_cast<const v4f*>(qh + ((size_t)b * NQ + q0 + row) * INNER + c4);
    *reinterpret_cast<v4f*>(&qhf[row][c4]) = v;
  }

  // q fragments (loaded once): dims d*16 + hi*8 + e
  const ushort* qptr = qhb + ((size_t)b * NQ + q0 + ln) * INNER + hi * 8;
  bf16x8 qf0 = *reinterpret_cast<const bf16x8*>(qptr);
  bf16x8 qf1 = *reinterpret_cast<const bf16x8*>(qptr + 16);
  bf16x8 qf2 = *reinterpret_cast<const bf16x8*>(qptr + 32);
  bf16x8 qf3 = *reinterpret_cast<const bf16x8*>(qptr + 48);

  const ushort* kptr = khb + ((size_t)b * NK + qg * 512 + ln) * INNER + hi * 8;

  float tv[8]; int ti[8];
  #pragma unroll
  for (int j = 0; j < 8; ++j) { tv[j] = NEG_INF; ti[j] = 0; }

  // prologue: tile 0 fragments
  bf16x8 kn0 = *reinterpret_cast<const bf16x8*>(kptr);
  bf16x8 kn1 = *reinterpret_cast<const bf16x8*>(kptr + 16);
  bf16x8 kn2 = *reinterpret_cast<const bf16x8*>(kptr + 32);
  bf16x8 kn3 = *reinterpret_cast<const bf16x8*>(kptr + 48);

  #pragma unroll 2
  for (int t16 = 0; t16 < 16; ++t16) {
    bf16x8 k0 = kn0, k1 = kn1, k2 = kn2, k3 = kn3;
    if (t16 + 1 < 16) {
      const ushort* np = kptr + (t16 + 1) * (32 * INNER);
      kn0 = *reinterpret_cast<const bf16x8*>(np);
      kn1 = *reinterpret_cast<const bf16x8*>(np + 16);
      kn2 = *reinterpret_cast<const bf16x8*>(np + 32);
      kn3 = *reinterpret_cast<const bf16x8*>(np + 48);
    }
    f32x16 acc;
    #pragma unroll
    for (int r = 0; r < 16; ++r) acc[r] = 0.f;
    acc = __builtin_amdgcn_mfma_f32_32x32x16_bf16(k0, qf0, acc, 0, 0, 0);
    acc = __builtin_amdgcn_mfma_f32_32x32x16_bf16(k1, qf1, acc, 0, 0, 0);
    acc = __builtin_amdgcn_mfma_f32_32x32x16_bf16(k2, qf2, acc, 0, 0, 0);
    acc = __builtin_amdgcn_mfma_f32_32x32x16_bf16(k3, qf3, acc, 0, 0, 0);

    float m0 = fmaxf(fmaxf(acc[0], acc[1]), fmaxf(acc[2], acc[3]));
    float m1 = fmaxf(fmaxf(acc[4], acc[5]), fmaxf(acc[6], acc[7]));
    float m2 = fmaxf(fmaxf(acc[8], acc[9]), fmaxf(acc[10], acc[11]));
    float m3 = fmaxf(fmaxf(acc[12], acc[13]), fmaxf(acc[14], acc[15]));
    float mx = fmaxf(fmaxf(m0, m1), fmaxf(m2, m3));
    if (mx > tv[7]) {
      const int kb0 = qg * 512 + t16 * 32 + 4 * hi;
      #pragma unroll
      for (int r = 0; r < 16; ++r) {
        float x = acc[r];
        if (x > tv[7]) insert8(tv, ti, x, kb0 + (r & 3) + 8 * (r >> 2));
      }
    }
  }

  // merge lane pair (kg, kg^32): both halves of each k-tile
  {
    float bv[8]; int bi[8];
    #pragma unroll
    for (int j = 0; j < 8; ++j) {
      bv[j] = __shfl_xor(tv[j], 32, 64);
      bi[j] = __shfl_xor(ti[j], 32, 64);
    }
    #pragma unroll
    for (int j = 0; j < 8; ++j)
      if (bv[j] > tv[7]) insert8(tv, ti, bv[j], bi[j]);
  }

  __syncthreads();
  if (kg < 32) {
    int base = ln * 66 + qg * 8;
    #pragma unroll
    for (int j = 0; j < 8; ++j) { mrgv[base + j] = tv[j]; mrgi[base + j] = ti[j]; }
  }
  __syncthreads();

  // merge 8 waves -> global bf16-order top-8 per row
  if (t < 32) {
    float rv[8]; int ri[8];
    #pragma unroll
    for (int j = 0; j < 8; ++j) { rv[j] = NEG_INF; ri[j] = 0; }
    for (int g = 0; g < 8; ++g) {
      #pragma unroll
      for (int j = 0; j < 8; ++j) {
        float x = mrgv[t * 66 + g * 8 + j];
        if (x > rv[7]) insert8(rv, ri, x, mrgi[t * 66 + g * 8 + j]);
      }
    }
    #pragma unroll
    for (int j = 0; j < 8; ++j) { candv[t][j] = rv[j]; candi[t][j] = ri[j]; }
  }
  __syncthreads();

  // exact f32 rescore of 8 candidates/row — bit-identical blocked order (r2)
  if (t < 256) {
    int row = t >> 3, j = t & 7;
    int idx = candi[row][j];
    const float* kcol = kh + ((size_t)b * NK + idx) * INNER;
    float acc = 0.f;
    #pragma unroll
    for (int dd = 0; dd < INNER; dd += 4) {
      v4f kv = *reinterpret_cast<const v4f*>(kcol + dd);
      v4f qv = *reinterpret_cast<const v4f*>(&qhf[row][dd]);
      float bs = qv[0] * kv[0];
      bs = fmaf(qv[1], kv[1], bs);
      bs = fmaf(qv[2], kv[2], bs);
      bs = fmaf(qv[3], kv[3], bs);
      acc += bs;
    }
    exactv[row][j] = acc;
  }
  __syncthreads();

  // top-5 of the 8 exact scores
  if (t < 32) {
    float rv[5]; int ri[5];
    #pragma unroll
    for (int j = 0; j < 5; ++j) { rv[j] = NEG_INF; ri[j] = 0; }
    #pragma unroll
    for (int j = 0; j < 8; ++j) {
      float x = exactv[t][j];
      if (x > rv[4]) insert5(rv, ri, x, candi[t][j]);
    }
    size_t rowg = (size_t)b * NQ + q0 + t;
    #pragma unroll
    for (int j = 0; j < 5; ++j) {
      topout[rowg * 10 + j]     = rv[j];
      topout[rowg * 10 + 5 + j] = __int_as_float(ri[j]);
    }
  }
}

// ---------- K3: fused zero-fill + softmax-of-survivors scatter (f32 out) -----
__global__ __launch_bounds__(256) void scatter_kernel(
    const float* __restrict__ topv, float* __restrict__ out)
{
  const int row = blockIdx.x;
  const int t   = threadIdx.x;
  const float* tp = topv + (size_t)row * 10;
  float v0 = tp[0], v1 = tp[1], v2 = tp[2], v3 = tp[3], v4 = tp[4];
  int i0 = __float_as_int(tp[5]);
  int i1 = __float_as_int(tp[6]);
  int i2 = __float_as_int(tp[7]);
  int i3 = __float_as_int(tp[8]);
  int i4 = __float_as_int(tp[9]);
  bool inc4 = (v4 >= v3);
  float e1 = expf(v1 - v0);
  float e2 = expf(v2 - v0);
  float e3 = expf(v3 - v0);
  float e4 = inc4 ? expf(v4 - v0) : 0.0f;
  float inv = 1.0f / (1.0f + e1 + e2 + e3 + e4);
  float w0 = inv, w1 = e1 * inv, w2 = e2 * inv, w3 = e3 * inv, w4 = e4 * inv;

  float* op = out + (size_t)row * NK + t * 16;
  #pragma unroll
  for (int u = 0; u < 4; ++u) {
    v4f o;
    #pragma unroll
    for (int e = 0; e < 4; ++e) {
      int col = t * 16 + u * 4 + e;
      o[e] = (col == i0) ? w0
           : (col == i1) ? w1
           : (col == i2) ? w2
           : (col == i3) ? w3
           : (col == i4) ? w4
           : 0.0f;
    }
    *reinterpret_cast<v4f*>(op + u * 4) = o;
  }
}

extern "C" void kernel_launch(void* const* d_in, const int* in_sizes, int n_in,
                              void* d_out, int out_size, void* d_ws, size_t ws_size,
                              hipStream_t stream) {
  const float* q  = (const float*)d_in[0];
  const float* k  = (const float*)d_in[1];
  const float* Wq = (const float*)d_in[3];
  const float* Wk = (const float*)d_in[4];

  const size_t NE = (size_t)BATCH * NQ * INNER;     // 1,048,576 per array
  float*  qh  = (float*)d_ws;                       // 4 MB
  float*  kh  = qh + NE;                            // 4 MB
  ushort* qhb = (ushort*)(kh + NE);                 // 2 MB
  ushort* khb = qhb + NE;                           // 2 MB
  float*  top = (float*)(khb + NE);                 // 640 KB

  proj_kernel<<<BATCH * NQ / 64, 256, 0, stream>>>(q, Wq, qh, 0.125f);
  proj_kernel<<<BATCH * NK / 64, 256, 0, stream>>>(k, Wk, kh, 1.0f);
  // qh,kh contiguous -> one convert pass produces qhb,khb (also contiguous)
  tobf16_kernel<<<(2 * NE) / (256 * 8), 256, 0, stream>>>(qh, qhb);
  filter_kernel<<<BATCH * (NQ / 32), 512, 0, stream>>>(qhb, khb, qh, kh, top);
  scatter_kernel<<<BATCH * NQ, 256, 0, stream>>>(top, (float*)d_out);
}

// Round 7
// 2226.000 us; speedup vs baseline: 1.7138x; 1.7138x over previous
//
#include <hip/hip_runtime.h>
#include <hip/hip_bf16.h>
#include <math.h>

typedef float v4f __attribute__((ext_vector_type(4)));
typedef short bf16x8 __attribute__((ext_vector_type(8)));   // 8 bf16 (4 VGPR)
typedef float f32x16 __attribute__((ext_vector_type(16)));

#define BATCH 4
#define NQ 4096
#define NK 4096
#define DIM 256
#define INNER 64
#define NEG_INF (-3.0e38f)

// ---------- K1: out[rows,64] = (X[rows,256] @ W[256,64]) * scale -------------
__global__ __launch_bounds__(256) void proj_kernel(
    const float* __restrict__ X, const float* __restrict__ W,
    float* __restrict__ out, float scale)
{
  __shared__ float xs[64 * 260];
  const int t = threadIdx.x;
  const int row0 = blockIdx.x * 64;

  #pragma unroll
  for (int it = 0; it < 16; ++it) {
    int idx = it * 256 + t;
    int r = idx >> 6, dq = idx & 63;
    v4f v = *reinterpret_cast<const v4f*>(X + (size_t)(row0 + r) * DIM + dq * 4);
    *reinterpret_cast<v4f*>(&xs[r * 260 + dq * 4]) = v;
  }
  __syncthreads();

  const int i0 = (t & 15) * 4;
  const int rg = t >> 4;
  float acc[4][4];
  #pragma unroll
  for (int p = 0; p < 4; ++p)
    #pragma unroll
    for (int i = 0; i < 4; ++i) acc[p][i] = 0.f;

  for (int d0 = 0; d0 < DIM; d0 += 4) {
    v4f w0 = *reinterpret_cast<const v4f*>(W + (d0 + 0) * INNER + i0);
    v4f w1 = *reinterpret_cast<const v4f*>(W + (d0 + 1) * INNER + i0);
    v4f w2 = *reinterpret_cast<const v4f*>(W + (d0 + 2) * INNER + i0);
    v4f w3 = *reinterpret_cast<const v4f*>(W + (d0 + 3) * INNER + i0);
    #pragma unroll
    for (int p = 0; p < 4; ++p) {
      v4f x = *reinterpret_cast<const v4f*>(&xs[(rg + 16 * p) * 260 + d0]);
      #pragma unroll
      for (int i = 0; i < 4; ++i) {
        float bs = x[0] * w0[i];
        bs = fmaf(x[1], w1[i], bs);
        bs = fmaf(x[2], w2[i], bs);
        bs = fmaf(x[3], w3[i], bs);
        acc[p][i] += bs;
      }
    }
  }
  #pragma unroll
  for (int p = 0; p < 4; ++p) {
    v4f o;
    #pragma unroll
    for (int i = 0; i < 4; ++i) o[i] = acc[p][i] * scale;
    *reinterpret_cast<v4f*>(out + (size_t)(row0 + rg + 16 * p) * INNER + i0) = o;
  }
}

// ---------- K1b: f32 -> bf16 (RNE), 8 elems/thread ---------------------------
__global__ __launch_bounds__(256) void tobf16_kernel(
    const float* __restrict__ in, ushort* __restrict__ out)
{
  int i = (blockIdx.x * 256 + threadIdx.x) * 8;
  v4f a = *reinterpret_cast<const v4f*>(in + i);
  v4f b = *reinterpret_cast<const v4f*>(in + i + 4);
  ushort o[8];
  #pragma unroll
  for (int e = 0; e < 4; ++e) {
    __hip_bfloat16 ha = __float2bfloat16(a[e]);
    __hip_bfloat16 hb = __float2bfloat16(b[e]);
    o[e]     = *reinterpret_cast<ushort*>(&ha);
    o[e + 4] = *reinterpret_cast<ushort*>(&hb);
  }
  *reinterpret_cast<bf16x8*>(out + i) = *reinterpret_cast<bf16x8*>(o);
}

// ---------- sorted insert helpers (call only when x > v[last]) ---------------
__device__ __forceinline__ void insert5(float (&v)[5], int (&ix)[5], float x, int xi) {
  bool g0 = x > v[0], g1 = x > v[1], g2 = x > v[2], g3 = x > v[3];
  v[4]  = g3 ? v[3] : x;                 ix[4] = g3 ? ix[3] : xi;
  v[3]  = g3 ? (g2 ? v[2] : x) : v[3];   ix[3] = g3 ? (g2 ? ix[2] : xi) : ix[3];
  v[2]  = g2 ? (g1 ? v[1] : x) : v[2];   ix[2] = g2 ? (g1 ? ix[1] : xi) : ix[2];
  v[1]  = g1 ? (g0 ? v[0] : x) : v[1];   ix[1] = g1 ? (g0 ? ix[0] : xi) : ix[1];
  v[0]  = g0 ? x : v[0];                 ix[0] = g0 ? xi : ix[0];
}

__device__ __forceinline__ void insert8(float (&v)[8], int (&ix)[8], float x, int xi) {
  bool g0 = x > v[0], g1 = x > v[1], g2 = x > v[2], g3 = x > v[3];
  bool g4 = x > v[4], g5 = x > v[5], g6 = x > v[6];
  v[7] = g6 ? v[6] : x;                 ix[7] = g6 ? ix[6] : xi;
  v[6] = g6 ? (g5 ? v[5] : x) : v[6];   ix[6] = g6 ? (g5 ? ix[5] : xi) : ix[6];
  v[5] = g5 ? (g4 ? v[4] : x) : v[5];   ix[5] = g5 ? (g4 ? ix[4] : xi) : ix[5];
  v[4] = g4 ? (g3 ? v[3] : x) : v[4];   ix[4] = g4 ? (g3 ? ix[3] : xi) : ix[4];
  v[3] = g3 ? (g2 ? v[2] : x) : v[3];   ix[3] = g3 ? (g2 ? ix[2] : xi) : ix[3];
  v[2] = g2 ? (g1 ? v[1] : x) : v[2];   ix[2] = g2 ? (g1 ? ix[1] : xi) : ix[2];
  v[1] = g1 ? (g0 ? v[0] : x) : v[1];   ix[1] = g1 ? (g0 ? ix[0] : xi) : ix[1];
  v[0] = g0 ? x : v[0];                 ix[0] = g0 ? xi : ix[0];
}

// ---------- K2: MFMA bf16 filter (top-8) + exact f32 rescore + top-5 ---------
// 256 thr = 4 waves. Block = 32 q-rows; wave qg owns k-cols [qg*1024,(qg+1)*1024)
// = 32 tiles. Swapped MFMA: acc = kh_tile(32x16) x qh_tile(16x32): each lane's
// 16 acc values belong to ONE q-row (col = lane&31); krow = (reg&3) + 8*(reg>>2)
// + 4*(lane>>5)  [validated bit-exact in round 6].
// All acc indexing is via literal-constant macro expansion (rule #20: no
// runtime indexing of ext_vector -> no scratch).
__global__ __launch_bounds__(256, 2) void filter_kernel(
    const ushort* __restrict__ qhb, const ushort* __restrict__ khb,
    const float* __restrict__ qh, const float* __restrict__ kh,
    float* __restrict__ topout)
{
  __shared__ float qhf[32][68];        // f32 q rows for exact rescore
  __shared__ float mrgv[32][33];       // [row][wave*8 + j]
  __shared__ int   mrgi[32][33];
  __shared__ int   candi[32][9];
  __shared__ float exactv[32][9];

  const int t   = threadIdx.x;
  const int bid = blockIdx.x;
  const int wg  = (bid & 7) * 64 + (bid >> 3);   // XCD swizzle (512 = 8*64)
  const int b   = wg >> 7;
  const int q0  = (wg & 127) * 32;
  const int qg  = t >> 6;                        // wave 0..3
  const int kg  = t & 63;                        // lane
  const int ln  = kg & 31;
  const int hi  = kg >> 5;

  // stage f32 q rows for rescore: 256 thr x 8 f32
  {
    int row = t >> 3, c8 = (t & 7) * 8;
    const float* src = qh + ((size_t)b * NQ + q0 + row) * INNER + c8;
    *reinterpret_cast<v4f*>(&qhf[row][c8])     = *reinterpret_cast<const v4f*>(src);
    *reinterpret_cast<v4f*>(&qhf[row][c8 + 4]) = *reinterpret_cast<const v4f*>(src + 4);
  }

  // q fragments (loaded once): dims d*16 + hi*8 + e
  const ushort* qptr = qhb + ((size_t)b * NQ + q0 + ln) * INNER + hi * 8;
  bf16x8 qf0 = *reinterpret_cast<const bf16x8*>(qptr);
  bf16x8 qf1 = *reinterpret_cast<const bf16x8*>(qptr + 16);
  bf16x8 qf2 = *reinterpret_cast<const bf16x8*>(qptr + 32);
  bf16x8 qf3 = *reinterpret_cast<const bf16x8*>(qptr + 48);

  const ushort* kptr = khb + ((size_t)b * NK + qg * 1024 + ln) * INNER + hi * 8;

  float tv[8]; int ti[8];
  #pragma unroll
  for (int j = 0; j < 8; ++j) { tv[j] = NEG_INF; ti[j] = 0; }

  for (int t32 = 0; t32 < 32; ++t32) {
    const ushort* kp = kptr + (size_t)t32 * (32 * INNER);
    bf16x8 k0 = *reinterpret_cast<const bf16x8*>(kp);
    bf16x8 k1 = *reinterpret_cast<const bf16x8*>(kp + 16);
    bf16x8 k2 = *reinterpret_cast<const bf16x8*>(kp + 32);
    bf16x8 k3 = *reinterpret_cast<const bf16x8*>(kp + 48);

    f32x16 acc = {0.f, 0.f, 0.f, 0.f, 0.f, 0.f, 0.f, 0.f,
                  0.f, 0.f, 0.f, 0.f, 0.f, 0.f, 0.f, 0.f};
    acc = __builtin_amdgcn_mfma_f32_32x32x16_bf16(k0, qf0, acc, 0, 0, 0);
    acc = __builtin_amdgcn_mfma_f32_32x32x16_bf16(k1, qf1, acc, 0, 0, 0);
    acc = __builtin_amdgcn_mfma_f32_32x32x16_bf16(k2, qf2, acc, 0, 0, 0);
    acc = __builtin_amdgcn_mfma_f32_32x32x16_bf16(k3, qf3, acc, 0, 0, 0);

    float m0 = fmaxf(fmaxf(acc[0],  acc[1]),  fmaxf(acc[2],  acc[3]));
    float m1 = fmaxf(fmaxf(acc[4],  acc[5]),  fmaxf(acc[6],  acc[7]));
    float m2 = fmaxf(fmaxf(acc[8],  acc[9]),  fmaxf(acc[10], acc[11]));
    float m3 = fmaxf(fmaxf(acc[12], acc[13]), fmaxf(acc[14], acc[15]));
    float mx = fmaxf(fmaxf(m0, m1), fmaxf(m2, m3));
    if (mx > tv[7]) {
      const int kb0 = qg * 1024 + t32 * 32 + 4 * hi;
      // literal-constant acc indexing only (no rolled loop -> no scratch)
#define PROC(r) { float x_ = acc[r]; \
                  if (x_ > tv[7]) insert8(tv, ti, x_, kb0 + ((r) & 3) + 8 * ((r) >> 2)); }
      PROC(0)  PROC(1)  PROC(2)  PROC(3)
      PROC(4)  PROC(5)  PROC(6)  PROC(7)
      PROC(8)  PROC(9)  PROC(10) PROC(11)
      PROC(12) PROC(13) PROC(14) PROC(15)
#undef PROC
    }
  }

  // merge lane pair (kg, kg^32): both krow-halves of each tile
  {
    float bv[8]; int bi[8];
    #pragma unroll
    for (int j = 0; j < 8; ++j) {
      bv[j] = __shfl_xor(tv[j], 32, 64);
      bi[j] = __shfl_xor(ti[j], 32, 64);
    }
    #pragma unroll
    for (int j = 0; j < 8; ++j)
      if (bv[j] > tv[7]) insert8(tv, ti, bv[j], bi[j]);
  }

  __syncthreads();
  if (kg < 32) {
    #pragma unroll
    for (int j = 0; j < 8; ++j) {
      mrgv[ln][qg * 8 + j] = tv[j];
      mrgi[ln][qg * 8 + j] = ti[j];
    }
  }
  __syncthreads();

  // merge 4 waves -> global bf16-order top-8 per row
  if (t < 32) {
    float rv[8]; int ri[8];
    #pragma unroll
    for (int j = 0; j < 8; ++j) { rv[j] = NEG_INF; ri[j] = 0; }
    #pragma unroll
    for (int g = 0; g < 4; ++g) {
      #pragma unroll
      for (int j = 0; j < 8; ++j) {
        float x = mrgv[t][g * 8 + j];
        if (x > rv[7]) insert8(rv, ri, x, mrgi[t][g * 8 + j]);
      }
    }
    #pragma unroll
    for (int j = 0; j < 8; ++j) candi[t][j] = ri[j];
  }
  __syncthreads();

  // exact f32 rescore of 8 candidates/row — bit-identical blocked order (r2)
  {
    int row = t >> 3, j = t & 7;
    int idx = candi[row][j];
    const float* kcol = kh + ((size_t)b * NK + idx) * INNER;
    float acc = 0.f;
    #pragma unroll
    for (int dd = 0; dd < INNER; dd += 4) {
      v4f kv = *reinterpret_cast<const v4f*>(kcol + dd);
      v4f qv = *reinterpret_cast<const v4f*>(&qhf[row][dd]);
      float bs = qv[0] * kv[0];
      bs = fmaf(qv[1], kv[1], bs);
      bs = fmaf(qv[2], kv[2], bs);
      bs = fmaf(qv[3], kv[3], bs);
      acc += bs;
    }
    exactv[row][j] = acc;
  }
  __syncthreads();

  // top-5 of the 8 exact scores
  if (t < 32) {
    float rv[5]; int ri[5];
    #pragma unroll
    for (int j = 0; j < 5; ++j) { rv[j] = NEG_INF; ri[j] = 0; }
    #pragma unroll
    for (int j = 0; j < 8; ++j) {
      float x = exactv[t][j];
      if (x > rv[4]) insert5(rv, ri, x, candi[t][j]);
    }
    size_t rowg = (size_t)b * NQ + q0 + t;
    #pragma unroll
    for (int j = 0; j < 5; ++j) {
      topout[rowg * 10 + j]     = rv[j];
      topout[rowg * 10 + 5 + j] = __int_as_float(ri[j]);
    }
  }
}

// ---------- K3: fused zero-fill + softmax-of-survivors scatter (f32 out) -----
__global__ __launch_bounds__(256) void scatter_kernel(
    const float* __restrict__ topv, float* __restrict__ out)
{
  const int row = blockIdx.x;
  const int t   = threadIdx.x;
  const float* tp = topv + (size_t)row * 10;
  float v0 = tp[0], v1 = tp[1], v2 = tp[2], v3 = tp[3], v4 = tp[4];
  int i0 = __float_as_int(tp[5]);
  int i1 = __float_as_int(tp[6]);
  int i2 = __float_as_int(tp[7]);
  int i3 = __float_as_int(tp[8]);
  int i4 = __float_as_int(tp[9]);
  bool inc4 = (v4 >= v3);
  float e1 = expf(v1 - v0);
  float e2 = expf(v2 - v0);
  float e3 = expf(v3 - v0);
  float e4 = inc4 ? expf(v4 - v0) : 0.0f;
  float inv = 1.0f / (1.0f + e1 + e2 + e3 + e4);
  float w0 = inv, w1 = e1 * inv, w2 = e2 * inv, w3 = e3 * inv, w4 = e4 * inv;

  float* op = out + (size_t)row * NK + t * 16;
  #pragma unroll
  for (int u = 0; u < 4; ++u) {
    v4f o;
    #pragma unroll
    for (int e = 0; e < 4; ++e) {
      int col = t * 16 + u * 4 + e;
      o[e] = (col == i0) ? w0
           : (col == i1) ? w1
           : (col == i2) ? w2
           : (col == i3) ? w3
           : (col == i4) ? w4
           : 0.0f;
    }
    *reinterpret_cast<v4f*>(op + u * 4) = o;
  }
}

extern "C" void kernel_launch(void* const* d_in, const int* in_sizes, int n_in,
                              void* d_out, int out_size, void* d_ws, size_t ws_size,
                              hipStream_t stream) {
  const float* q  = (const float*)d_in[0];
  const float* k  = (const float*)d_in[1];
  const float* Wq = (const float*)d_in[3];
  const float* Wk = (const float*)d_in[4];

  const size_t NE = (size_t)BATCH * NQ * INNER;     // 1,048,576 per array
  float*  qh  = (float*)d_ws;                       // 4 MB
  float*  kh  = qh + NE;                            // 4 MB
  ushort* qhb = (ushort*)(kh + NE);                 // 2 MB
  ushort* khb = qhb + NE;                           // 2 MB
  float*  top = (float*)(khb + NE);                 // 640 KB

  proj_kernel<<<BATCH * NQ / 64, 256, 0, stream>>>(q, Wq, qh, 0.125f);
  proj_kernel<<<BATCH * NK / 64, 256, 0, stream>>>(k, Wk, kh, 1.0f);
  // qh,kh contiguous -> one convert pass produces qhb,khb (also contiguous)
  tobf16_kernel<<<(2 * NE) / (256 * 8), 256, 0, stream>>>(qh, qhb);
  filter_kernel<<<BATCH * (NQ / 32), 256, 0, stream>>>(qhb, khb, qh, kh, top);
  scatter_kernel<<<BATCH * NQ, 256, 0, stream>>>(top, (float*)d_out);
}

// Round 8
// 252.761 us; speedup vs baseline: 15.0930x; 8.8067x over previous
//
#include <hip/hip_runtime.h>
#include <hip/hip_bf16.h>
#include <math.h>

typedef float v4f __attribute__((ext_vector_type(4)));
typedef short bf16x8 __attribute__((ext_vector_type(8)));   // 8 bf16 (4 VGPR)
typedef float f32x16 __attribute__((ext_vector_type(16)));

#define BATCH 4
#define NQ 4096
#define NK 4096
#define DIM 256
#define INNER 64
#define NEG_INF (-3.0e38f)

// ---------- K1: out[rows,64] = (X[rows,256] @ W[256,64]) * scale -------------
__global__ __launch_bounds__(256) void proj_kernel(
    const float* __restrict__ X, const float* __restrict__ W,
    float* __restrict__ out, float scale)
{
  __shared__ float xs[64 * 260];
  const int t = threadIdx.x;
  const int row0 = blockIdx.x * 64;

  #pragma unroll
  for (int it = 0; it < 16; ++it) {
    int idx = it * 256 + t;
    int r = idx >> 6, dq = idx & 63;
    v4f v = *reinterpret_cast<const v4f*>(X + (size_t)(row0 + r) * DIM + dq * 4);
    *reinterpret_cast<v4f*>(&xs[r * 260 + dq * 4]) = v;
  }
  __syncthreads();

  const int i0 = (t & 15) * 4;
  const int rg = t >> 4;
  float acc[4][4];
  #pragma unroll
  for (int p = 0; p < 4; ++p)
    #pragma unroll
    for (int i = 0; i < 4; ++i) acc[p][i] = 0.f;

  for (int d0 = 0; d0 < DIM; d0 += 4) {
    v4f w0 = *reinterpret_cast<const v4f*>(W + (d0 + 0) * INNER + i0);
    v4f w1 = *reinterpret_cast<const v4f*>(W + (d0 + 1) * INNER + i0);
    v4f w2 = *reinterpret_cast<const v4f*>(W + (d0 + 2) * INNER + i0);
    v4f w3 = *reinterpret_cast<const v4f*>(W + (d0 + 3) * INNER + i0);
    #pragma unroll
    for (int p = 0; p < 4; ++p) {
      v4f x = *reinterpret_cast<const v4f*>(&xs[(rg + 16 * p) * 260 + d0]);
      #pragma unroll
      for (int i = 0; i < 4; ++i) {
        float bs = x[0] * w0[i];
        bs = fmaf(x[1], w1[i], bs);
        bs = fmaf(x[2], w2[i], bs);
        bs = fmaf(x[3], w3[i], bs);
        acc[p][i] += bs;
      }
    }
  }
  #pragma unroll
  for (int p = 0; p < 4; ++p) {
    v4f o;
    #pragma unroll
    for (int i = 0; i < 4; ++i) o[i] = acc[p][i] * scale;
    *reinterpret_cast<v4f*>(out + (size_t)(row0 + rg + 16 * p) * INNER + i0) = o;
  }
}

// ---------- K1b: f32 -> bf16 (RNE), 8 elems/thread ---------------------------
__global__ __launch_bounds__(256) void tobf16_kernel(
    const float* __restrict__ in, ushort* __restrict__ out)
{
  int i = (blockIdx.x * 256 + threadIdx.x) * 8;
  v4f a = *reinterpret_cast<const v4f*>(in + i);
  v4f b = *reinterpret_cast<const v4f*>(in + i + 4);
  ushort o[8];
  #pragma unroll
  for (int e = 0; e < 4; ++e) {
    __hip_bfloat16 ha = __float2bfloat16(a[e]);
    __hip_bfloat16 hb = __float2bfloat16(b[e]);
    o[e]     = *reinterpret_cast<ushort*>(&ha);
    o[e + 4] = *reinterpret_cast<ushort*>(&hb);
  }
  *reinterpret_cast<bf16x8*>(out + i) = *reinterpret_cast<bf16x8*>(o);
}

// ---------- sorted insert helpers (cold-path arrays) -------------------------
__device__ __forceinline__ void insert5(float (&v)[5], int (&ix)[5], float x, int xi) {
  bool g0 = x > v[0], g1 = x > v[1], g2 = x > v[2], g3 = x > v[3];
  v[4]  = g3 ? v[3] : x;                 ix[4] = g3 ? ix[3] : xi;
  v[3]  = g3 ? (g2 ? v[2] : x) : v[3];   ix[3] = g3 ? (g2 ? ix[2] : xi) : ix[3];
  v[2]  = g2 ? (g1 ? v[1] : x) : v[2];   ix[2] = g2 ? (g1 ? ix[1] : xi) : ix[2];
  v[1]  = g1 ? (g0 ? v[0] : x) : v[1];   ix[1] = g1 ? (g0 ? ix[0] : xi) : ix[1];
  v[0]  = g0 ? x : v[0];                 ix[0] = g0 ? xi : ix[0];
}

__device__ __forceinline__ void insert8(float (&v)[8], int (&ix)[8], float x, int xi) {
  bool g0 = x > v[0], g1 = x > v[1], g2 = x > v[2], g3 = x > v[3];
  bool g4 = x > v[4], g5 = x > v[5], g6 = x > v[6];
  v[7] = g6 ? v[6] : x;                 ix[7] = g6 ? ix[6] : xi;
  v[6] = g6 ? (g5 ? v[5] : x) : v[6];   ix[6] = g6 ? (g5 ? ix[5] : xi) : ix[6];
  v[5] = g5 ? (g4 ? v[4] : x) : v[5];   ix[5] = g5 ? (g4 ? ix[4] : xi) : ix[5];
  v[4] = g4 ? (g3 ? v[3] : x) : v[4];   ix[4] = g4 ? (g3 ? ix[3] : xi) : ix[4];
  v[3] = g3 ? (g2 ? v[2] : x) : v[3];   ix[3] = g3 ? (g2 ? ix[2] : xi) : ix[3];
  v[2] = g2 ? (g1 ? v[1] : x) : v[2];   ix[2] = g2 ? (g1 ? ix[1] : xi) : ix[2];
  v[1] = g1 ? (g0 ? v[0] : x) : v[1];   ix[1] = g1 ? (g0 ? ix[0] : xi) : ix[1];
  v[0] = g0 ? x : v[0];                 ix[0] = g0 ? xi : ix[0];
}

// hot-loop insert on NAMED SCALARS only (no arrays, no references):
// precondition x_ > v7.
#define INS8(x_, xi_) {                                              \
  bool g0 = (x_) > v0, g1 = (x_) > v1, g2 = (x_) > v2, g3 = (x_) > v3; \
  bool g4 = (x_) > v4, g5 = (x_) > v5, g6 = (x_) > v6;               \
  v7 = g6 ? v6 : (x_);            i7 = g6 ? i6 : (xi_);              \
  v6 = g6 ? (g5 ? v5 : (x_)) : v6; i6 = g6 ? (g5 ? i5 : (xi_)) : i6; \
  v5 = g5 ? (g4 ? v4 : (x_)) : v5; i5 = g5 ? (g4 ? i4 : (xi_)) : i5; \
  v4 = g4 ? (g3 ? v3 : (x_)) : v4; i4 = g4 ? (g3 ? i3 : (xi_)) : i4; \
  v3 = g3 ? (g2 ? v2 : (x_)) : v3; i3 = g3 ? (g2 ? i2 : (xi_)) : i3; \
  v2 = g2 ? (g1 ? v1 : (x_)) : v2; i2 = g2 ? (g1 ? i1 : (xi_)) : i2; \
  v1 = g1 ? (g0 ? v0 : (x_)) : v1; i1 = g1 ? (g0 ? i0 : (xi_)) : i1; \
  v0 = g0 ? (x_) : v0;            i0 = g0 ? (xi_) : i0; }

// ---------- K2: MFMA bf16 filter (top-8) + exact f32 rescore + top-5 ---------
// 256 thr = 4 waves. Block = 32 q-rows; wave qg owns k-cols [qg*1024,(qg+1)*1024)
// = 32 tiles. Swapped MFMA: acc = kh_tile(32x16) x qh_tile(16x32): each lane's
// 16 acc values belong to ONE q-row (col = lane&31); krow = (reg&3)+8*(reg>>2)
// +4*(lane>>5)  [validated bit-exact r6/r7]. Hot loop touches ONLY named
// scalars + literal acc extracts -> nothing can be demoted to scratch.
__global__ __launch_bounds__(256) void filter_kernel(
    const ushort* __restrict__ qhb, const ushort* __restrict__ khb,
    const float* __restrict__ qh, const float* __restrict__ kh,
    float* __restrict__ topout)
{
  __shared__ float qhf[32][68];        // f32 q rows for exact rescore
  __shared__ float mrgv[32][33];       // [row][wave*8 + j]
  __shared__ int   mrgi[32][33];
  __shared__ int   candi[32][9];
  __shared__ float exactv[32][9];

  const int t   = threadIdx.x;
  const int bid = blockIdx.x;
  const int wg  = (bid & 7) * 64 + (bid >> 3);   // XCD swizzle (512 = 8*64)
  const int b   = wg >> 7;
  const int q0  = (wg & 127) * 32;
  const int qg  = t >> 6;                        // wave 0..3
  const int kg  = t & 63;                        // lane
  const int ln  = kg & 31;
  const int hi  = kg >> 5;

  // stage f32 q rows for rescore: 256 thr x 8 f32
  {
    int row = t >> 3, c8 = (t & 7) * 8;
    const float* src = qh + ((size_t)b * NQ + q0 + row) * INNER + c8;
    *reinterpret_cast<v4f*>(&qhf[row][c8])     = *reinterpret_cast<const v4f*>(src);
    *reinterpret_cast<v4f*>(&qhf[row][c8 + 4]) = *reinterpret_cast<const v4f*>(src + 4);
  }

  // q fragments (loaded once): dims d*16 + hi*8 + e
  const ushort* qptr = qhb + ((size_t)b * NQ + q0 + ln) * INNER + hi * 8;
  bf16x8 qf0 = *reinterpret_cast<const bf16x8*>(qptr);
  bf16x8 qf1 = *reinterpret_cast<const bf16x8*>(qptr + 16);
  bf16x8 qf2 = *reinterpret_cast<const bf16x8*>(qptr + 32);
  bf16x8 qf3 = *reinterpret_cast<const bf16x8*>(qptr + 48);

  const ushort* kptr = khb + ((size_t)b * NK + qg * 1024 + ln) * INNER + hi * 8;

  float v0 = NEG_INF, v1 = NEG_INF, v2 = NEG_INF, v3 = NEG_INF;
  float v4 = NEG_INF, v5 = NEG_INF, v6 = NEG_INF, v7 = NEG_INF;
  int   i0 = 0, i1 = 0, i2 = 0, i3 = 0, i4 = 0, i5 = 0, i6 = 0, i7 = 0;

  for (int t32 = 0; t32 < 32; ++t32) {
    const ushort* kp = kptr + (size_t)t32 * (32 * INNER);
    bf16x8 k0 = *reinterpret_cast<const bf16x8*>(kp);
    bf16x8 k1 = *reinterpret_cast<const bf16x8*>(kp + 16);
    bf16x8 k2 = *reinterpret_cast<const bf16x8*>(kp + 32);
    bf16x8 k3 = *reinterpret_cast<const bf16x8*>(kp + 48);

    f32x16 acc = {0.f, 0.f, 0.f, 0.f, 0.f, 0.f, 0.f, 0.f,
                  0.f, 0.f, 0.f, 0.f, 0.f, 0.f, 0.f, 0.f};
    acc = __builtin_amdgcn_mfma_f32_32x32x16_bf16(k0, qf0, acc, 0, 0, 0);
    acc = __builtin_amdgcn_mfma_f32_32x32x16_bf16(k1, qf1, acc, 0, 0, 0);
    acc = __builtin_amdgcn_mfma_f32_32x32x16_bf16(k2, qf2, acc, 0, 0, 0);
    acc = __builtin_amdgcn_mfma_f32_32x32x16_bf16(k3, qf3, acc, 0, 0, 0);

    float m0 = fmaxf(fmaxf(acc[0],  acc[1]),  fmaxf(acc[2],  acc[3]));
    float m1 = fmaxf(fmaxf(acc[4],  acc[5]),  fmaxf(acc[6],  acc[7]));
    float m2 = fmaxf(fmaxf(acc[8],  acc[9]),  fmaxf(acc[10], acc[11]));
    float m3 = fmaxf(fmaxf(acc[12], acc[13]), fmaxf(acc[14], acc[15]));
    float mx = fmaxf(fmaxf(m0, m1), fmaxf(m2, m3));
    if (mx > v7) {
      const int kb0 = qg * 1024 + t32 * 32 + 4 * hi;
#define PROC(r) { float x_ = acc[r]; \
                  if (x_ > v7) INS8(x_, kb0 + ((r) & 3) + 8 * ((r) >> 2)); }
      PROC(0)  PROC(1)  PROC(2)  PROC(3)
      PROC(4)  PROC(5)  PROC(6)  PROC(7)
      PROC(8)  PROC(9)  PROC(10) PROC(11)
      PROC(12) PROC(13) PROC(14) PROC(15)
#undef PROC
    }
  }

  // merge lane pair (kg, kg^32): both krow-halves of each tile (named scalars)
  {
    float bv0 = __shfl_xor(v0, 32, 64), bv1 = __shfl_xor(v1, 32, 64);
    float bv2 = __shfl_xor(v2, 32, 64), bv3 = __shfl_xor(v3, 32, 64);
    float bv4 = __shfl_xor(v4, 32, 64), bv5 = __shfl_xor(v5, 32, 64);
    float bv6 = __shfl_xor(v6, 32, 64), bv7 = __shfl_xor(v7, 32, 64);
    int bi0 = __shfl_xor(i0, 32, 64), bi1 = __shfl_xor(i1, 32, 64);
    int bi2 = __shfl_xor(i2, 32, 64), bi3 = __shfl_xor(i3, 32, 64);
    int bi4 = __shfl_xor(i4, 32, 64), bi5 = __shfl_xor(i5, 32, 64);
    int bi6 = __shfl_xor(i6, 32, 64), bi7 = __shfl_xor(i7, 32, 64);
    if (bv0 > v7) INS8(bv0, bi0);
    if (bv1 > v7) INS8(bv1, bi1);
    if (bv2 > v7) INS8(bv2, bi2);
    if (bv3 > v7) INS8(bv3, bi3);
    if (bv4 > v7) INS8(bv4, bi4);
    if (bv5 > v7) INS8(bv5, bi5);
    if (bv6 > v7) INS8(bv6, bi6);
    if (bv7 > v7) INS8(bv7, bi7);
  }

  __syncthreads();
  if (kg < 32) {
    mrgv[ln][qg * 8 + 0] = v0; mrgi[ln][qg * 8 + 0] = i0;
    mrgv[ln][qg * 8 + 1] = v1; mrgi[ln][qg * 8 + 1] = i1;
    mrgv[ln][qg * 8 + 2] = v2; mrgi[ln][qg * 8 + 2] = i2;
    mrgv[ln][qg * 8 + 3] = v3; mrgi[ln][qg * 8 + 3] = i3;
    mrgv[ln][qg * 8 + 4] = v4; mrgi[ln][qg * 8 + 4] = i4;
    mrgv[ln][qg * 8 + 5] = v5; mrgi[ln][qg * 8 + 5] = i5;
    mrgv[ln][qg * 8 + 6] = v6; mrgi[ln][qg * 8 + 6] = i6;
    mrgv[ln][qg * 8 + 7] = v7; mrgi[ln][qg * 8 + 7] = i7;
  }
  __syncthreads();

  // merge 4 waves -> global bf16-order top-8 per row (cold, arrays ok)
  if (t < 32) {
    float rv[8]; int ri[8];
    #pragma unroll
    for (int j = 0; j < 8; ++j) { rv[j] = NEG_INF; ri[j] = 0; }
    #pragma unroll
    for (int g = 0; g < 4; ++g) {
      #pragma unroll
      for (int j = 0; j < 8; ++j) {
        float x = mrgv[t][g * 8 + j];
        if (x > rv[7]) insert8(rv, ri, x, mrgi[t][g * 8 + j]);
      }
    }
    #pragma unroll
    for (int j = 0; j < 8; ++j) candi[t][j] = ri[j];
  }
  __syncthreads();

  // exact f32 rescore of 8 candidates/row — bit-identical blocked order (r2)
  {
    int row = t >> 3, j = t & 7;
    int idx = candi[row][j];
    const float* kcol = kh + ((size_t)b * NK + idx) * INNER;
    float acc = 0.f;
    #pragma unroll
    for (int dd = 0; dd < INNER; dd += 4) {
      v4f kv = *reinterpret_cast<const v4f*>(kcol + dd);
      v4f qv = *reinterpret_cast<const v4f*>(&qhf[row][dd]);
      float bs = qv[0] * kv[0];
      bs = fmaf(qv[1], kv[1], bs);
      bs = fmaf(qv[2], kv[2], bs);
      bs = fmaf(qv[3], kv[3], bs);
      acc += bs;
    }
    exactv[row][j] = acc;
  }
  __syncthreads();

  // top-5 of the 8 exact scores
  if (t < 32) {
    float rv[5]; int ri[5];
    #pragma unroll
    for (int j = 0; j < 5; ++j) { rv[j] = NEG_INF; ri[j] = 0; }
    #pragma unroll
    for (int j = 0; j < 8; ++j) {
      float x = exactv[t][j];
      if (x > rv[4]) insert5(rv, ri, x, candi[t][j]);
    }
    size_t rowg = (size_t)b * NQ + q0 + t;
    #pragma unroll
    for (int j = 0; j < 5; ++j) {
      topout[rowg * 10 + j]     = rv[j];
      topout[rowg * 10 + 5 + j] = __int_as_float(ri[j]);
    }
  }
}

// ---------- K3: fused zero-fill + softmax-of-survivors scatter (f32 out) -----
__global__ __launch_bounds__(256) void scatter_kernel(
    const float* __restrict__ topv, float* __restrict__ out)
{
  const int row = blockIdx.x;
  const int t   = threadIdx.x;
  const float* tp = topv + (size_t)row * 10;
  float v0 = tp[0], v1 = tp[1], v2 = tp[2], v3 = tp[3], v4 = tp[4];
  int i0 = __float_as_int(tp[5]);
  int i1 = __float_as_int(tp[6]);
  int i2 = __float_as_int(tp[7]);
  int i3 = __float_as_int(tp[8]);
  int i4 = __float_as_int(tp[9]);
  bool inc4 = (v4 >= v3);
  float e1 = expf(v1 - v0);
  float e2 = expf(v2 - v0);
  float e3 = expf(v3 - v0);
  float e4 = inc4 ? expf(v4 - v0) : 0.0f;
  float inv = 1.0f / (1.0f + e1 + e2 + e3 + e4);
  float w0 = inv, w1 = e1 * inv, w2 = e2 * inv, w3 = e3 * inv, w4 = e4 * inv;

  float* op = out + (size_t)row * NK + t * 16;
  #pragma unroll
  for (int u = 0; u < 4; ++u) {
    v4f o;
    #pragma unroll
    for (int e = 0; e < 4; ++e) {
      int col = t * 16 + u * 4 + e;
      o[e] = (col == i0) ? w0
           : (col == i1) ? w1
           : (col == i2) ? w2
           : (col == i3) ? w3
           : (col == i4) ? w4
           : 0.0f;
    }
    *reinterpret_cast<v4f*>(op + u * 4) = o;
  }
}

extern "C" void kernel_launch(void* const* d_in, const int* in_sizes, int n_in,
                              void* d_out, int out_size, void* d_ws, size_t ws_size,
                              hipStream_t stream) {
  const float* q  = (const float*)d_in[0];
  const float* k  = (const float*)d_in[1];
  const float* Wq = (const float*)d_in[3];
  const float* Wk = (const float*)d_in[4];

  const size_t NE = (size_t)BATCH * NQ * INNER;     // 1,048,576 per array
  float*  qh  = (float*)d_ws;                       // 4 MB
  float*  kh  = qh + NE;                            // 4 MB
  ushort* qhb = (ushort*)(kh + NE);                 // 2 MB
  ushort* khb = qhb + NE;                           // 2 MB
  float*  top = (float*)(khb + NE);                 // 640 KB

  proj_kernel<<<BATCH * NQ / 64, 256, 0, stream>>>(q, Wq, qh, 0.125f);
  proj_kernel<<<BATCH * NK / 64, 256, 0, stream>>>(k, Wk, kh, 1.0f);
  // qh,kh contiguous -> one convert pass produces qhb,khb (also contiguous)
  tobf16_kernel<<<(2 * NE) / (256 * 8), 256, 0, stream>>>(qh, qhb);
  filter_kernel<<<BATCH * (NQ / 32), 256, 0, stream>>>(qhb, khb, qh, kh, top);
  scatter_kernel<<<BATCH * NQ, 256, 0, stream>>>(top, (float*)d_out);
}

// Round 9
// 207.732 us; speedup vs baseline: 18.3646x; 1.2168x over previous
//
#include <hip/hip_runtime.h>
#include <hip/hip_bf16.h>
#include <math.h>

typedef float v4f __attribute__((ext_vector_type(4)));
typedef short bf16x8 __attribute__((ext_vector_type(8)));   // 8 bf16 (4 VGPR)
typedef float f32x16 __attribute__((ext_vector_type(16)));

#define BATCH 4
#define NQ 4096
#define NK 4096
#define DIM 256
#define INNER 64
#define NEG_INF (-3.0e38f)
#define CAP 64

// ---------- K1: out[rows,64] = (X[rows,256] @ W[256,64]) * scale -------------
__global__ __launch_bounds__(256) void proj_kernel(
    const float* __restrict__ X, const float* __restrict__ W,
    float* __restrict__ out, float scale)
{
  __shared__ float xs[64 * 260];
  const int t = threadIdx.x;
  const int row0 = blockIdx.x * 64;

  #pragma unroll
  for (int it = 0; it < 16; ++it) {
    int idx = it * 256 + t;
    int r = idx >> 6, dq = idx & 63;
    v4f v = *reinterpret_cast<const v4f*>(X + (size_t)(row0 + r) * DIM + dq * 4);
    *reinterpret_cast<v4f*>(&xs[r * 260 + dq * 4]) = v;
  }
  __syncthreads();

  const int i0 = (t & 15) * 4;
  const int rg = t >> 4;
  float acc[4][4];
  #pragma unroll
  for (int p = 0; p < 4; ++p)
    #pragma unroll
    for (int i = 0; i < 4; ++i) acc[p][i] = 0.f;

  for (int d0 = 0; d0 < DIM; d0 += 4) {
    v4f w0 = *reinterpret_cast<const v4f*>(W + (d0 + 0) * INNER + i0);
    v4f w1 = *reinterpret_cast<const v4f*>(W + (d0 + 1) * INNER + i0);
    v4f w2 = *reinterpret_cast<const v4f*>(W + (d0 + 2) * INNER + i0);
    v4f w3 = *reinterpret_cast<const v4f*>(W + (d0 + 3) * INNER + i0);
    #pragma unroll
    for (int p = 0; p < 4; ++p) {
      v4f x = *reinterpret_cast<const v4f*>(&xs[(rg + 16 * p) * 260 + d0]);
      #pragma unroll
      for (int i = 0; i < 4; ++i) {
        float bs = x[0] * w0[i];
        bs = fmaf(x[1], w1[i], bs);
        bs = fmaf(x[2], w2[i], bs);
        bs = fmaf(x[3], w3[i], bs);
        acc[p][i] += bs;
      }
    }
  }
  #pragma unroll
  for (int p = 0; p < 4; ++p) {
    v4f o;
    #pragma unroll
    for (int i = 0; i < 4; ++i) o[i] = acc[p][i] * scale;
    *reinterpret_cast<v4f*>(out + (size_t)(row0 + rg + 16 * p) * INNER + i0) = o;
  }
}

// ---------- K1b: f32 -> bf16 (RNE), 8 elems/thread ---------------------------
__global__ __launch_bounds__(256) void tobf16_kernel(
    const float* __restrict__ in, ushort* __restrict__ out)
{
  int i = (blockIdx.x * 256 + threadIdx.x) * 8;
  v4f a = *reinterpret_cast<const v4f*>(in + i);
  v4f b = *reinterpret_cast<const v4f*>(in + i + 4);
  ushort o[8];
  #pragma unroll
  for (int e = 0; e < 4; ++e) {
    __hip_bfloat16 ha = __float2bfloat16(a[e]);
    __hip_bfloat16 hb = __float2bfloat16(b[e]);
    o[e]     = *reinterpret_cast<ushort*>(&ha);
    o[e + 4] = *reinterpret_cast<ushort*>(&hb);
  }
  *reinterpret_cast<bf16x8*>(out + i) = *reinterpret_cast<bf16x8*>(o);
}

// ---------- cold-path sorted inserts -----------------------------------------
__device__ __forceinline__ void insert5(float (&v)[5], int (&ix)[5], float x, int xi) {
  bool g0 = x > v[0], g1 = x > v[1], g2 = x > v[2], g3 = x > v[3];
  v[4]  = g3 ? v[3] : x;                 ix[4] = g3 ? ix[3] : xi;
  v[3]  = g3 ? (g2 ? v[2] : x) : v[3];   ix[3] = g3 ? (g2 ? ix[2] : xi) : ix[3];
  v[2]  = g2 ? (g1 ? v[1] : x) : v[2];   ix[2] = g2 ? (g1 ? ix[1] : xi) : ix[2];
  v[1]  = g1 ? (g0 ? v[0] : x) : v[1];   ix[1] = g1 ? (g0 ? ix[0] : xi) : ix[1];
  v[0]  = g0 ? x : v[0];                 ix[0] = g0 ? xi : ix[0];
}

// value-only top-8 insert (cold; precondition x > v[7])
__device__ __forceinline__ void insert8v(float (&v)[8], float x) {
  bool g0 = x > v[0], g1 = x > v[1], g2 = x > v[2], g3 = x > v[3];
  bool g4 = x > v[4], g5 = x > v[5], g6 = x > v[6];
  v[7] = g6 ? v[6] : x;
  v[6] = g6 ? (g5 ? v[5] : x) : v[6];
  v[5] = g5 ? (g4 ? v[4] : x) : v[5];
  v[4] = g4 ? (g3 ? v[3] : x) : v[4];
  v[3] = g3 ? (g2 ? v[2] : x) : v[3];
  v[2] = g2 ? (g1 ? v[1] : x) : v[2];
  v[1] = g1 ? (g0 ? v[0] : x) : v[1];
  v[0] = g0 ? x : v[0];
}

// ---------- K2: 2-pass MFMA filter: threshold tau + compaction + exact rescore
// 512 thr = 8 waves. Block = 32 q-rows; wave qg owns k-cols [qg*512,(qg+1)*512)
// = 16 tiles of 32. Swapped MFMA (layout validated bit-exact r6-r8): lane's 16
// acc belong to ONE q-row (row = lane&31); k = base + (r&3)+8*(r>>2)+4*hi.
// Pass1: branchless strip-max only. tau[row] = 8th-largest of 16 strip-maxes
// (>=8 values >= tau ==> candidate set {x >= tau} is a superset of top-8).
// Pass2: recompute tiles, compact candidates (~11/row) to LDS. Exact f32
// rescore (bit-identical blocked order) -> top-5.
__global__ __launch_bounds__(512) void filter_kernel(
    const ushort* __restrict__ qhb, const ushort* __restrict__ khb,
    const float* __restrict__ qh, const float* __restrict__ kh,
    float* __restrict__ topout)
{
  __shared__ float qhf[32][68];        // f32 q rows for exact rescore
  __shared__ float sm[32][16];         // per-row strip maxes
  __shared__ float tau[32];
  __shared__ int   cnt[32];
  __shared__ int   cand[32][CAP];
  __shared__ float exactv[32][CAP];

  const int t   = threadIdx.x;
  const int bid = blockIdx.x;
  const int wg  = (bid & 7) * 64 + (bid >> 3);   // XCD swizzle (512 = 8*64)
  const int b   = wg >> 7;
  const int q0  = (wg & 127) * 32;
  const int qg  = t >> 6;                        // wave 0..7
  const int kg  = t & 63;                        // lane
  const int ln  = kg & 31;                       // row within block
  const int hi  = kg >> 5;

  // stage f32 q rows for rescore; init counters
  if (t < 256) {
    int row = t >> 3, c8 = (t & 7) * 8;
    const float* src = qh + ((size_t)b * NQ + q0 + row) * INNER + c8;
    *reinterpret_cast<v4f*>(&qhf[row][c8])     = *reinterpret_cast<const v4f*>(src);
    *reinterpret_cast<v4f*>(&qhf[row][c8 + 4]) = *reinterpret_cast<const v4f*>(src + 4);
  }
  if (t < 32) cnt[t] = 0;

  // q fragments (loaded once): dims d*16 + hi*8 + e
  const ushort* qptr = qhb + ((size_t)b * NQ + q0 + ln) * INNER + hi * 8;
  bf16x8 qf0 = *reinterpret_cast<const bf16x8*>(qptr);
  bf16x8 qf1 = *reinterpret_cast<const bf16x8*>(qptr + 16);
  bf16x8 qf2 = *reinterpret_cast<const bf16x8*>(qptr + 32);
  bf16x8 qf3 = *reinterpret_cast<const bf16x8*>(qptr + 48);

  const ushort* kptr = khb + ((size_t)b * NK + qg * 512 + ln) * INNER + hi * 8;

  // ---- Pass 1: branchless strip max --------------------------------------
  float smax = NEG_INF;
  for (int t16 = 0; t16 < 16; ++t16) {
    const ushort* kp = kptr + (size_t)t16 * (32 * INNER);
    bf16x8 k0 = *reinterpret_cast<const bf16x8*>(kp);
    bf16x8 k1 = *reinterpret_cast<const bf16x8*>(kp + 16);
    bf16x8 k2 = *reinterpret_cast<const bf16x8*>(kp + 32);
    bf16x8 k3 = *reinterpret_cast<const bf16x8*>(kp + 48);

    f32x16 acc = {0.f, 0.f, 0.f, 0.f, 0.f, 0.f, 0.f, 0.f,
                  0.f, 0.f, 0.f, 0.f, 0.f, 0.f, 0.f, 0.f};
    acc = __builtin_amdgcn_mfma_f32_32x32x16_bf16(k0, qf0, acc, 0, 0, 0);
    acc = __builtin_amdgcn_mfma_f32_32x32x16_bf16(k1, qf1, acc, 0, 0, 0);
    acc = __builtin_amdgcn_mfma_f32_32x32x16_bf16(k2, qf2, acc, 0, 0, 0);
    acc = __builtin_amdgcn_mfma_f32_32x32x16_bf16(k3, qf3, acc, 0, 0, 0);

    float m0 = fmaxf(fmaxf(acc[0],  acc[1]),  fmaxf(acc[2],  acc[3]));
    float m1 = fmaxf(fmaxf(acc[4],  acc[5]),  fmaxf(acc[6],  acc[7]));
    float m2 = fmaxf(fmaxf(acc[8],  acc[9]),  fmaxf(acc[10], acc[11]));
    float m3 = fmaxf(fmaxf(acc[12], acc[13]), fmaxf(acc[14], acc[15]));
    smax = fmaxf(smax, fmaxf(fmaxf(m0, m1), fmaxf(m2, m3)));
  }
  sm[ln][qg * 2 + hi] = smax;
  __syncthreads();

  // tau[row] = 8th-largest of the 16 strip maxes (cold, 1 thread/row)
  if (t < 32) {
    float rv[8];
    #pragma unroll
    for (int j = 0; j < 8; ++j) rv[j] = NEG_INF;
    #pragma unroll
    for (int s = 0; s < 16; ++s) {
      float x = sm[t][s];
      if (x > rv[7]) insert8v(rv, x);
    }
    tau[t] = rv[7];
  }
  __syncthreads();

  // ---- Pass 2: recompute + compact candidates >= tau ----------------------
  const float tl = tau[ln];
  for (int t16 = 0; t16 < 16; ++t16) {
    const ushort* kp = kptr + (size_t)t16 * (32 * INNER);
    bf16x8 k0 = *reinterpret_cast<const bf16x8*>(kp);
    bf16x8 k1 = *reinterpret_cast<const bf16x8*>(kp + 16);
    bf16x8 k2 = *reinterpret_cast<const bf16x8*>(kp + 32);
    bf16x8 k3 = *reinterpret_cast<const bf16x8*>(kp + 48);

    f32x16 acc = {0.f, 0.f, 0.f, 0.f, 0.f, 0.f, 0.f, 0.f,
                  0.f, 0.f, 0.f, 0.f, 0.f, 0.f, 0.f, 0.f};
    acc = __builtin_amdgcn_mfma_f32_32x32x16_bf16(k0, qf0, acc, 0, 0, 0);
    acc = __builtin_amdgcn_mfma_f32_32x32x16_bf16(k1, qf1, acc, 0, 0, 0);
    acc = __builtin_amdgcn_mfma_f32_32x32x16_bf16(k2, qf2, acc, 0, 0, 0);
    acc = __builtin_amdgcn_mfma_f32_32x32x16_bf16(k3, qf3, acc, 0, 0, 0);

    const int kb0 = qg * 512 + t16 * 32 + 4 * hi;
#define CHK(r) { float x_ = acc[r]; \
                 if (x_ >= tl) { \
                   int p_ = atomicAdd(&cnt[ln], 1); \
                   if (p_ < CAP) cand[ln][p_] = kb0 + ((r) & 3) + 8 * ((r) >> 2); } }
    CHK(0)  CHK(1)  CHK(2)  CHK(3)
    CHK(4)  CHK(5)  CHK(6)  CHK(7)
    CHK(8)  CHK(9)  CHK(10) CHK(11)
    CHK(12) CHK(13) CHK(14) CHK(15)
#undef CHK
  }
  __syncthreads();

  // ---- exact f32 rescore (bit-identical blocked order, validated r6-r8) ---
  {
    int row = t >> 4, j0 = t & 15;
    int n = min(cnt[row], CAP);
    for (int jj = j0; jj < n; jj += 16) {
      int idx = cand[row][jj];
      const float* kcol = kh + ((size_t)b * NK + idx) * INNER;
      float acc = 0.f;
      #pragma unroll
      for (int dd = 0; dd < INNER; dd += 4) {
        v4f kv = *reinterpret_cast<const v4f*>(kcol + dd);
        v4f qv = *reinterpret_cast<const v4f*>(&qhf[row][dd]);
        float bs = qv[0] * kv[0];
        bs = fmaf(qv[1], kv[1], bs);
        bs = fmaf(qv[2], kv[2], bs);
        bs = fmaf(qv[3], kv[3], bs);
        acc += bs;
      }
      exactv[row][jj] = acc;
    }
  }
  __syncthreads();

  // ---- top-5 of exact candidate scores ------------------------------------
  if (t < 32) {
    int n = min(cnt[t], CAP);
    float rv[5]; int ri[5];
    #pragma unroll
    for (int j = 0; j < 5; ++j) { rv[j] = NEG_INF; ri[j] = 0; }
    for (int j = 0; j < n; ++j) {
      float x = exactv[t][j];
      if (x > rv[4]) insert5(rv, ri, x, cand[t][j]);
    }
    size_t rowg = (size_t)b * NQ + q0 + t;
    #pragma unroll
    for (int j = 0; j < 5; ++j) {
      topout[rowg * 10 + j]     = rv[j];
      topout[rowg * 10 + 5 + j] = __int_as_float(ri[j]);
    }
  }
}

// ---------- K3: fused zero-fill + softmax-of-survivors scatter (f32 out) -----
__global__ __launch_bounds__(256) void scatter_kernel(
    const float* __restrict__ topv, float* __restrict__ out)
{
  const int row = blockIdx.x;
  const int t   = threadIdx.x;
  const float* tp = topv + (size_t)row * 10;
  float v0 = tp[0], v1 = tp[1], v2 = tp[2], v3 = tp[3], v4 = tp[4];
  int i0 = __float_as_int(tp[5]);
  int i1 = __float_as_int(tp[6]);
  int i2 = __float_as_int(tp[7]);
  int i3 = __float_as_int(tp[8]);
  int i4 = __float_as_int(tp[9]);
  bool inc4 = (v4 >= v3);
  float e1 = expf(v1 - v0);
  float e2 = expf(v2 - v0);
  float e3 = expf(v3 - v0);
  float e4 = inc4 ? expf(v4 - v0) : 0.0f;
  float inv = 1.0f / (1.0f + e1 + e2 + e3 + e4);
  float w0 = inv, w1 = e1 * inv, w2 = e2 * inv, w3 = e3 * inv, w4 = e4 * inv;

  float* op = out + (size_t)row * NK + t * 16;
  #pragma unroll
  for (int u = 0; u < 4; ++u) {
    v4f o;
    #pragma unroll
    for (int e = 0; e < 4; ++e) {
      int col = t * 16 + u * 4 + e;
      o[e] = (col == i0) ? w0
           : (col == i1) ? w1
           : (col == i2) ? w2
           : (col == i3) ? w3
           : (col == i4) ? w4
           : 0.0f;
    }
    *reinterpret_cast<v4f*>(op + u * 4) = o;
  }
}

extern "C" void kernel_launch(void* const* d_in, const int* in_sizes, int n_in,
                              void* d_out, int out_size, void* d_ws, size_t ws_size,
                              hipStream_t stream) {
  const float* q  = (const float*)d_in[0];
  const float* k  = (const float*)d_in[1];
  const float* Wq = (const float*)d_in[3];
  const float* Wk = (const float*)d_in[4];

  const size_t NE = (size_t)BATCH * NQ * INNER;     // 1,048,576 per array
  float*  qh  = (float*)d_ws;                       // 4 MB
  float*  kh  = qh + NE;                            // 4 MB
  ushort* qhb = (ushort*)(kh + NE);                 // 2 MB
  ushort* khb = qhb + NE;                           // 2 MB
  float*  top = (float*)(khb + NE);                 // 640 KB

  proj_kernel<<<BATCH * NQ / 64, 256, 0, stream>>>(q, Wq, qh, 0.125f);
  proj_kernel<<<BATCH * NK / 64, 256, 0, stream>>>(k, Wk, kh, 1.0f);
  // qh,kh contiguous -> one convert pass produces qhb,khb (also contiguous)
  tobf16_kernel<<<(2 * NE) / (256 * 8), 256, 0, stream>>>(qh, qhb);
  filter_kernel<<<BATCH * (NQ / 32), 512, 0, stream>>>(qhb, khb, qh, kh, top);
  scatter_kernel<<<BATCH * NQ, 256, 0, stream>>>(top, (float*)d_out);
}

// Round 10
// 154.538 us; speedup vs baseline: 24.6860x; 1.3442x over previous
//
#include <hip/hip_runtime.h>
#include <hip/hip_bf16.h>
#include <math.h>

typedef float v4f __attribute__((ext_vector_type(4)));
typedef short bf16x8 __attribute__((ext_vector_type(8)));   // 8 bf16 (4 VGPR)
typedef float f32x16 __attribute__((ext_vector_type(16)));

#define BATCH 4
#define NQ 4096
#define NK 4096
#define DIM 256
#define INNER 64
#define NEG_INF (-3.0e38f)
#define CAP 64

// ---------- K1: fused q/k projection, f32 + bf16 outputs ---------------------
// grid 1024: bid<512 -> q slab, else k slab. 32 rows/block (LDS 33 KB ->
// 2 blocks/CU). Per-output accumulation order identical to rounds 2-9
// (bit-exact); bf16 = RNE convert of the same f32 values (== tobf16_kernel).
__global__ __launch_bounds__(256) void proj_kernel(
    const float* __restrict__ q, const float* __restrict__ k,
    const float* __restrict__ Wq, const float* __restrict__ Wk,
    float* __restrict__ qh, float* __restrict__ kh,
    ushort* __restrict__ qhb, ushort* __restrict__ khb)
{
  __shared__ float xs[32 * 260];
  const int bid = blockIdx.x;
  const bool isq = bid < 512;
  const float* X   = isq ? q : k;
  const float* W   = isq ? Wq : Wk;
  float*   out     = isq ? qh : kh;
  ushort*  outb    = isq ? qhb : khb;
  const float scale = isq ? 0.125f : 1.0f;
  const int row0 = (isq ? bid : bid - 512) * 32;
  const int t = threadIdx.x;

  #pragma unroll
  for (int it = 0; it < 8; ++it) {
    int idx = it * 256 + t;
    int r = idx >> 6, dq = idx & 63;
    v4f v = *reinterpret_cast<const v4f*>(X + (size_t)(row0 + r) * DIM + dq * 4);
    *reinterpret_cast<v4f*>(&xs[r * 260 + dq * 4]) = v;
  }
  __syncthreads();

  const int i0 = (t & 15) * 4;
  const int rg = t >> 4;
  float acc[2][4];
  #pragma unroll
  for (int p = 0; p < 2; ++p)
    #pragma unroll
    for (int i = 0; i < 4; ++i) acc[p][i] = 0.f;

  for (int d0 = 0; d0 < DIM; d0 += 4) {
    v4f w0 = *reinterpret_cast<const v4f*>(W + (d0 + 0) * INNER + i0);
    v4f w1 = *reinterpret_cast<const v4f*>(W + (d0 + 1) * INNER + i0);
    v4f w2 = *reinterpret_cast<const v4f*>(W + (d0 + 2) * INNER + i0);
    v4f w3 = *reinterpret_cast<const v4f*>(W + (d0 + 3) * INNER + i0);
    #pragma unroll
    for (int p = 0; p < 2; ++p) {
      v4f x = *reinterpret_cast<const v4f*>(&xs[(rg + 16 * p) * 260 + d0]);
      #pragma unroll
      for (int i = 0; i < 4; ++i) {
        float bs = x[0] * w0[i];                 // bit-exact blocked order
        bs = fmaf(x[1], w1[i], bs);
        bs = fmaf(x[2], w2[i], bs);
        bs = fmaf(x[3], w3[i], bs);
        acc[p][i] += bs;
      }
    }
  }
  #pragma unroll
  for (int p = 0; p < 2; ++p) {
    v4f o;
    ushort ob[4];
    #pragma unroll
    for (int i = 0; i < 4; ++i) {
      o[i] = acc[p][i] * scale;
      __hip_bfloat16 h = __float2bfloat16(o[i]);
      ob[i] = *reinterpret_cast<ushort*>(&h);
    }
    size_t row = (size_t)(row0 + rg + 16 * p);
    *reinterpret_cast<v4f*>(out + row * INNER + i0) = o;
    *reinterpret_cast<uint2*>(outb + row * INNER + i0) = *reinterpret_cast<uint2*>(ob);
  }
}

// ---------- cold-path sorted inserts -----------------------------------------
__device__ __forceinline__ void insert5(float (&v)[5], int (&ix)[5], float x, int xi) {
  bool g0 = x > v[0], g1 = x > v[1], g2 = x > v[2], g3 = x > v[3];
  v[4]  = g3 ? v[3] : x;                 ix[4] = g3 ? ix[3] : xi;
  v[3]  = g3 ? (g2 ? v[2] : x) : v[3];   ix[3] = g3 ? (g2 ? ix[2] : xi) : ix[3];
  v[2]  = g2 ? (g1 ? v[1] : x) : v[2];   ix[2] = g2 ? (g1 ? ix[1] : xi) : ix[2];
  v[1]  = g1 ? (g0 ? v[0] : x) : v[1];   ix[1] = g1 ? (g0 ? ix[0] : xi) : ix[1];
  v[0]  = g0 ? x : v[0];                 ix[0] = g0 ? xi : ix[0];
}

// value-only top-8 insert (cold; precondition x > v[7])
__device__ __forceinline__ void insert8v(float (&v)[8], float x) {
  bool g0 = x > v[0], g1 = x > v[1], g2 = x > v[2], g3 = x > v[3];
  bool g4 = x > v[4], g5 = x > v[5], g6 = x > v[6];
  v[7] = g6 ? v[6] : x;
  v[6] = g6 ? (g5 ? v[5] : x) : v[6];
  v[5] = g5 ? (g4 ? v[4] : x) : v[5];
  v[4] = g4 ? (g3 ? v[3] : x) : v[4];
  v[3] = g3 ? (g2 ? v[2] : x) : v[3];
  v[2] = g2 ? (g1 ? v[1] : x) : v[2];
  v[1] = g1 ? (g0 ? v[0] : x) : v[1];
  v[0] = g0 ? x : v[0];
}

// ---------- K2: 2-pass MFMA filter + exact rescore + fused row output --------
// 512 thr = 8 waves; block owns 32 q-rows. Pass1: strip-max; tau = 8th-largest
// of 16 strip maxes; pass2: compact {x >= tau} (~11/row); exact f32 rescore
// (bit-identical blocked order) -> top-5 -> softmax -> zero-fill + scatter the
// block's 32 output rows (coalesced v4f zeros, then <=160 scattered stores).
__global__ __launch_bounds__(512) void filter_kernel(
    const ushort* __restrict__ qhb, const ushort* __restrict__ khb,
    const float* __restrict__ qh, const float* __restrict__ kh,
    float* __restrict__ out)
{
  __shared__ float qhf[32][68];        // f32 q rows for exact rescore
  __shared__ float sm[32][16];         // per-row strip maxes
  __shared__ float tau[32];
  __shared__ int   cnt[32];
  __shared__ int   cand[32][CAP];
  __shared__ float exactv[32][CAP];
  __shared__ float w5[32][5];
  __shared__ int   id5[32][6];         // [5] = surviving count (4 or 5)

  const int t   = threadIdx.x;
  const int bid = blockIdx.x;
  const int wg  = (bid & 7) * 64 + (bid >> 3);   // XCD swizzle (512 = 8*64)
  const int b   = wg >> 7;
  const int q0  = (wg & 127) * 32;
  const int qg  = t >> 6;                        // wave 0..7
  const int kg  = t & 63;                        // lane
  const int ln  = kg & 31;                       // q-row within block
  const int hi  = kg >> 5;

  if (t < 256) {
    int row = t >> 3, c8 = (t & 7) * 8;
    const float* src = qh + ((size_t)b * NQ + q0 + row) * INNER + c8;
    *reinterpret_cast<v4f*>(&qhf[row][c8])     = *reinterpret_cast<const v4f*>(src);
    *reinterpret_cast<v4f*>(&qhf[row][c8 + 4]) = *reinterpret_cast<const v4f*>(src + 4);
  }
  if (t < 32) cnt[t] = 0;

  const ushort* qptr = qhb + ((size_t)b * NQ + q0 + ln) * INNER + hi * 8;
  bf16x8 qf0 = *reinterpret_cast<const bf16x8*>(qptr);
  bf16x8 qf1 = *reinterpret_cast<const bf16x8*>(qptr + 16);
  bf16x8 qf2 = *reinterpret_cast<const bf16x8*>(qptr + 32);
  bf16x8 qf3 = *reinterpret_cast<const bf16x8*>(qptr + 48);

  const ushort* kptr = khb + ((size_t)b * NK + qg * 512 + ln) * INNER + hi * 8;

  // ---- Pass 1: branchless strip max --------------------------------------
  float smax = NEG_INF;
  for (int t16 = 0; t16 < 16; ++t16) {
    const ushort* kp = kptr + (size_t)t16 * (32 * INNER);
    bf16x8 k0 = *reinterpret_cast<const bf16x8*>(kp);
    bf16x8 k1 = *reinterpret_cast<const bf16x8*>(kp + 16);
    bf16x8 k2 = *reinterpret_cast<const bf16x8*>(kp + 32);
    bf16x8 k3 = *reinterpret_cast<const bf16x8*>(kp + 48);

    f32x16 acc = {0.f, 0.f, 0.f, 0.f, 0.f, 0.f, 0.f, 0.f,
                  0.f, 0.f, 0.f, 0.f, 0.f, 0.f, 0.f, 0.f};
    acc = __builtin_amdgcn_mfma_f32_32x32x16_bf16(k0, qf0, acc, 0, 0, 0);
    acc = __builtin_amdgcn_mfma_f32_32x32x16_bf16(k1, qf1, acc, 0, 0, 0);
    acc = __builtin_amdgcn_mfma_f32_32x32x16_bf16(k2, qf2, acc, 0, 0, 0);
    acc = __builtin_amdgcn_mfma_f32_32x32x16_bf16(k3, qf3, acc, 0, 0, 0);

    float m0 = fmaxf(fmaxf(acc[0],  acc[1]),  fmaxf(acc[2],  acc[3]));
    float m1 = fmaxf(fmaxf(acc[4],  acc[5]),  fmaxf(acc[6],  acc[7]));
    float m2 = fmaxf(fmaxf(acc[8],  acc[9]),  fmaxf(acc[10], acc[11]));
    float m3 = fmaxf(fmaxf(acc[12], acc[13]), fmaxf(acc[14], acc[15]));
    smax = fmaxf(smax, fmaxf(fmaxf(m0, m1), fmaxf(m2, m3)));
  }
  sm[ln][qg * 2 + hi] = smax;
  __syncthreads();

  if (t < 32) {
    float rv[8];
    #pragma unroll
    for (int j = 0; j < 8; ++j) rv[j] = NEG_INF;
    #pragma unroll
    for (int s = 0; s < 16; ++s) {
      float x = sm[t][s];
      if (x > rv[7]) insert8v(rv, x);
    }
    tau[t] = rv[7];
  }
  __syncthreads();

  // ---- Pass 2: recompute + compact candidates >= tau ----------------------
  const float tl = tau[ln];
  for (int t16 = 0; t16 < 16; ++t16) {
    const ushort* kp = kptr + (size_t)t16 * (32 * INNER);
    bf16x8 k0 = *reinterpret_cast<const bf16x8*>(kp);
    bf16x8 k1 = *reinterpret_cast<const bf16x8*>(kp + 16);
    bf16x8 k2 = *reinterpret_cast<const bf16x8*>(kp + 32);
    bf16x8 k3 = *reinterpret_cast<const bf16x8*>(kp + 48);

    f32x16 acc = {0.f, 0.f, 0.f, 0.f, 0.f, 0.f, 0.f, 0.f,
                  0.f, 0.f, 0.f, 0.f, 0.f, 0.f, 0.f, 0.f};
    acc = __builtin_amdgcn_mfma_f32_32x32x16_bf16(k0, qf0, acc, 0, 0, 0);
    acc = __builtin_amdgcn_mfma_f32_32x32x16_bf16(k1, qf1, acc, 0, 0, 0);
    acc = __builtin_amdgcn_mfma_f32_32x32x16_bf16(k2, qf2, acc, 0, 0, 0);
    acc = __builtin_amdgcn_mfma_f32_32x32x16_bf16(k3, qf3, acc, 0, 0, 0);

    const int kb0 = qg * 512 + t16 * 32 + 4 * hi;
#define CHK(r) { float x_ = acc[r]; \
                 if (x_ >= tl) { \
                   int p_ = atomicAdd(&cnt[ln], 1); \
                   if (p_ < CAP) cand[ln][p_] = kb0 + ((r) & 3) + 8 * ((r) >> 2); } }
    CHK(0)  CHK(1)  CHK(2)  CHK(3)
    CHK(4)  CHK(5)  CHK(6)  CHK(7)
    CHK(8)  CHK(9)  CHK(10) CHK(11)
    CHK(12) CHK(13) CHK(14) CHK(15)
#undef CHK
  }
  __syncthreads();

  // ---- exact f32 rescore (bit-identical blocked order) --------------------
  {
    int row = t >> 4, j0 = t & 15;
    int n = min(cnt[row], CAP);
    for (int jj = j0; jj < n; jj += 16) {
      int idx = cand[row][jj];
      const float* kcol = kh + ((size_t)b * NK + idx) * INNER;
      float acc = 0.f;
      #pragma unroll
      for (int dd = 0; dd < INNER; dd += 4) {
        v4f kv = *reinterpret_cast<const v4f*>(kcol + dd);
        v4f qv = *reinterpret_cast<const v4f*>(&qhf[row][dd]);
        float bs = qv[0] * kv[0];
        bs = fmaf(qv[1], kv[1], bs);
        bs = fmaf(qv[2], kv[2], bs);
        bs = fmaf(qv[3], kv[3], bs);
        acc += bs;
      }
      exactv[row][jj] = acc;
    }
  }
  __syncthreads();

  // ---- top-5 of exact scores + softmax (same arithmetic as old scatter) ---
  if (t < 32) {
    int n = min(cnt[t], CAP);
    float rv[5]; int ri[5];
    #pragma unroll
    for (int j = 0; j < 5; ++j) { rv[j] = NEG_INF; ri[j] = 0; }
    for (int j = 0; j < n; ++j) {
      float x = exactv[t][j];
      if (x > rv[4]) insert5(rv, ri, x, cand[t][j]);
    }
    bool inc4 = (rv[4] >= rv[3]);
    float e1 = expf(rv[1] - rv[0]);
    float e2 = expf(rv[2] - rv[0]);
    float e3 = expf(rv[3] - rv[0]);
    float e4 = inc4 ? expf(rv[4] - rv[0]) : 0.0f;
    float inv = 1.0f / (1.0f + e1 + e2 + e3 + e4);
    w5[t][0] = inv;      w5[t][1] = e1 * inv;  w5[t][2] = e2 * inv;
    w5[t][3] = e3 * inv; w5[t][4] = e4 * inv;
    #pragma unroll
    for (int j = 0; j < 5; ++j) id5[t][j] = ri[j];
    id5[t][5] = inc4 ? 5 : 4;
  }
  __syncthreads();

  // ---- fused output: coalesced zero-fill of 32 rows, then scatter ---------
  float* obase = out + ((size_t)b * NQ + q0) * (size_t)NK;
  v4f z = {0.f, 0.f, 0.f, 0.f};
  #pragma unroll 8
  for (int u = 0; u < 64; ++u)
    *reinterpret_cast<v4f*>(obase + (size_t)u * 2048 + t * 4) = z;
  __syncthreads();                     // drains vmcnt -> zeros ordered first
  if (t < 160) {
    int row = t / 5, j = t % 5;
    if (j < id5[row][5])
      obase[(size_t)row * NK + id5[row][j]] = w5[row][j];
  }
}

extern "C" void kernel_launch(void* const* d_in, const int* in_sizes, int n_in,
                              void* d_out, int out_size, void* d_ws, size_t ws_size,
                              hipStream_t stream) {
  const float* q  = (const float*)d_in[0];
  const float* k  = (const float*)d_in[1];
  const float* Wq = (const float*)d_in[3];
  const float* Wk = (const float*)d_in[4];

  const size_t NE = (size_t)BATCH * NQ * INNER;     // 1,048,576 per array
  float*  qh  = (float*)d_ws;                       // 4 MB
  float*  kh  = qh + NE;                            // 4 MB
  ushort* qhb = (ushort*)(kh + NE);                 // 2 MB
  ushort* khb = qhb + NE;                           // 2 MB

  proj_kernel<<<1024, 256, 0, stream>>>(q, k, Wq, Wk, qh, kh, qhb, khb);
  filter_kernel<<<512, 512, 0, stream>>>(qhb, khb, qh, kh, (float*)d_out);
}

// Round 11
// 120.460 us; speedup vs baseline: 31.6696x; 1.2829x over previous
//
#include <hip/hip_runtime.h>
#include <hip/hip_bf16.h>
#include <math.h>

typedef float v4f __attribute__((ext_vector_type(4)));
typedef short bf16x8 __attribute__((ext_vector_type(8)));   // 8 bf16 (4 VGPR)
typedef float f32x16 __attribute__((ext_vector_type(16)));

#define BATCH 4
#define NQ 4096
#define NK 4096
#define DIM 256
#define INNER 64
#define NEG_INF (-3.0e38f)
#define CAP 64

// ---------- K1: fused q/k projection, f32 + bf16 outputs ---------------------
// grid 1024: bid<512 -> q slab (row-major bf16), else k slab (bf16 stored in
// MFMA-fragment-major tile layout: [tile32][d:4][hi:2][row:32][e:8] so filter's
// fragment loads are fully coalesced). Values bit-identical to rounds 2-10.
__global__ __launch_bounds__(256) void proj_kernel(
    const float* __restrict__ q, const float* __restrict__ k,
    const float* __restrict__ Wq, const float* __restrict__ Wk,
    float* __restrict__ qh, float* __restrict__ kh,
    ushort* __restrict__ qhb, ushort* __restrict__ khb)
{
  __shared__ float xs[32 * 260];
  const int bid = blockIdx.x;
  const bool isq = bid < 512;
  const float* X   = isq ? q : k;
  const float* W   = isq ? Wq : Wk;
  float*   out     = isq ? qh : kh;
  const float scale = isq ? 0.125f : 1.0f;
  const int row0 = (isq ? bid : bid - 512) * 32;
  const int t = threadIdx.x;

  #pragma unroll
  for (int it = 0; it < 8; ++it) {
    int idx = it * 256 + t;
    int r = idx >> 6, dq = idx & 63;
    v4f v = *reinterpret_cast<const v4f*>(X + (size_t)(row0 + r) * DIM + dq * 4);
    *reinterpret_cast<v4f*>(&xs[r * 260 + dq * 4]) = v;
  }
  __syncthreads();

  const int i0 = (t & 15) * 4;
  const int rg = t >> 4;
  float acc[2][4];
  #pragma unroll
  for (int p = 0; p < 2; ++p)
    #pragma unroll
    for (int i = 0; i < 4; ++i) acc[p][i] = 0.f;

  for (int d0 = 0; d0 < DIM; d0 += 4) {
    v4f w0 = *reinterpret_cast<const v4f*>(W + (d0 + 0) * INNER + i0);
    v4f w1 = *reinterpret_cast<const v4f*>(W + (d0 + 1) * INNER + i0);
    v4f w2 = *reinterpret_cast<const v4f*>(W + (d0 + 2) * INNER + i0);
    v4f w3 = *reinterpret_cast<const v4f*>(W + (d0 + 3) * INNER + i0);
    #pragma unroll
    for (int p = 0; p < 2; ++p) {
      v4f x = *reinterpret_cast<const v4f*>(&xs[(rg + 16 * p) * 260 + d0]);
      #pragma unroll
      for (int i = 0; i < 4; ++i) {
        float bs = x[0] * w0[i];                 // bit-exact blocked order
        bs = fmaf(x[1], w1[i], bs);
        bs = fmaf(x[2], w2[i], bs);
        bs = fmaf(x[3], w3[i], bs);
        acc[p][i] += bs;
      }
    }
  }

  const int d  = i0 >> 4;            // dim-group 0..3
  const int hi = (i0 >> 3) & 1;      // half 0..1
  const int e0 = i0 & 7;             // 0 or 4
  #pragma unroll
  for (int p = 0; p < 2; ++p) {
    v4f o;
    ushort ob[4];
    #pragma unroll
    for (int i = 0; i < 4; ++i) {
      o[i] = acc[p][i] * scale;
      __hip_bfloat16 h = __float2bfloat16(o[i]);
      ob[i] = *reinterpret_cast<ushort*>(&h);
    }
    int rr = rg + 16 * p;
    size_t row = (size_t)(row0 + rr);
    *reinterpret_cast<v4f*>(out + row * INNER + i0) = o;
    if (isq) {
      *reinterpret_cast<uint2*>(qhb + row * INNER + i0) =
          *reinterpret_cast<uint2*>(ob);
    } else {
      // fragment-major: tile = row0/32 = bid-512
      size_t off = (size_t)(bid - 512) * 2048 + d * 512 + hi * 256 + rr * 8 + e0;
      *reinterpret_cast<uint2*>(khb + off) = *reinterpret_cast<uint2*>(ob);
    }
  }
}

// ---------- cold-path sorted inserts -----------------------------------------
__device__ __forceinline__ void insert5(float (&v)[5], int (&ix)[5], float x, int xi) {
  bool g0 = x > v[0], g1 = x > v[1], g2 = x > v[2], g3 = x > v[3];
  v[4]  = g3 ? v[3] : x;                 ix[4] = g3 ? ix[3] : xi;
  v[3]  = g3 ? (g2 ? v[2] : x) : v[3];   ix[3] = g3 ? (g2 ? ix[2] : xi) : ix[3];
  v[2]  = g2 ? (g1 ? v[1] : x) : v[2];   ix[2] = g2 ? (g1 ? ix[1] : xi) : ix[2];
  v[1]  = g1 ? (g0 ? v[0] : x) : v[1];   ix[1] = g1 ? (g0 ? ix[0] : xi) : ix[1];
  v[0]  = g0 ? x : v[0];                 ix[0] = g0 ? xi : ix[0];
}

// value-only top-8 insert (cold; precondition x > v[7])
__device__ __forceinline__ void insert8v(float (&v)[8], float x) {
  bool g0 = x > v[0], g1 = x > v[1], g2 = x > v[2], g3 = x > v[3];
  bool g4 = x > v[4], g5 = x > v[5], g6 = x > v[6];
  v[7] = g6 ? v[6] : x;
  v[6] = g6 ? (g5 ? v[5] : x) : v[6];
  v[5] = g5 ? (g4 ? v[4] : x) : v[5];
  v[4] = g4 ? (g3 ? v[3] : x) : v[4];
  v[3] = g3 ? (g2 ? v[2] : x) : v[3];
  v[2] = g2 ? (g1 ? v[1] : x) : v[2];
  v[1] = g1 ? (g0 ? v[0] : x) : v[1];
  v[0] = g0 ? x : v[0];
}

// ---------- K2: 2-pass MFMA filter + exact rescore + fused row output --------
// 512 thr = 8 waves; block owns 32 q-rows. khb is fragment-major (coalesced
// 1KB fragment loads). The block's 268MB-share of output zeros is issued
// 2 v4f-stores per tile-iteration, draining under compute; barriers order
// zeros before the <=160 scattered weight stores.
__global__ __launch_bounds__(512) void filter_kernel(
    const ushort* __restrict__ qhb, const ushort* __restrict__ khb,
    const float* __restrict__ qh, const float* __restrict__ kh,
    float* __restrict__ out)
{
  __shared__ float qhf[32][68];
  __shared__ float sm[32][16];
  __shared__ float tau[32];
  __shared__ int   cnt[32];
  __shared__ int   cand[32][CAP];
  __shared__ float exactv[32][CAP];
  __shared__ float w5[32][5];
  __shared__ int   id5[32][6];

  const int t   = threadIdx.x;
  const int bid = blockIdx.x;
  const int wg  = (bid & 7) * 64 + (bid >> 3);   // XCD swizzle (512 = 8*64)
  const int b   = wg >> 7;
  const int q0  = (wg & 127) * 32;
  const int qg  = t >> 6;                        // wave 0..7
  const int kg  = t & 63;                        // lane
  const int ln  = kg & 31;
  const int hi  = kg >> 5;

  float* obase = out + ((size_t)b * NQ + q0) * (size_t)NK;
  const v4f z = {0.f, 0.f, 0.f, 0.f};

  if (t < 256) {
    int row = t >> 3, c8 = (t & 7) * 8;
    const float* src = qh + ((size_t)b * NQ + q0 + row) * INNER + c8;
    *reinterpret_cast<v4f*>(&qhf[row][c8])     = *reinterpret_cast<const v4f*>(src);
    *reinterpret_cast<v4f*>(&qhf[row][c8 + 4]) = *reinterpret_cast<const v4f*>(src + 4);
  }
  if (t < 32) cnt[t] = 0;

  const ushort* qptr = qhb + ((size_t)b * NQ + q0 + ln) * INNER + hi * 8;
  bf16x8 qf0 = *reinterpret_cast<const bf16x8*>(qptr);
  bf16x8 qf1 = *reinterpret_cast<const bf16x8*>(qptr + 16);
  bf16x8 qf2 = *reinterpret_cast<const bf16x8*>(qptr + 32);
  bf16x8 qf3 = *reinterpret_cast<const bf16x8*>(qptr + 48);

  // wave qg's 16 tiles, fragment-major
  const ushort* ktile = khb + ((size_t)b * 128 + qg * 16) * 2048;

  // ---- Pass 1: branchless strip max + interleaved zero-fill ---------------
  float smax = NEG_INF;
  for (int t16 = 0; t16 < 16; ++t16) {
    const ushort* tb = ktile + (size_t)t16 * 2048;
    bf16x8 k0 = *reinterpret_cast<const bf16x8*>(tb +        kg * 8);
    bf16x8 k1 = *reinterpret_cast<const bf16x8*>(tb +  512 + kg * 8);
    bf16x8 k2 = *reinterpret_cast<const bf16x8*>(tb + 1024 + kg * 8);
    bf16x8 k3 = *reinterpret_cast<const bf16x8*>(tb + 1536 + kg * 8);

    *reinterpret_cast<v4f*>(obase + (size_t)(t16 * 2)     * 2048 + t * 4) = z;
    *reinterpret_cast<v4f*>(obase + (size_t)(t16 * 2 + 1) * 2048 + t * 4) = z;

    f32x16 acc = {0.f, 0.f, 0.f, 0.f, 0.f, 0.f, 0.f, 0.f,
                  0.f, 0.f, 0.f, 0.f, 0.f, 0.f, 0.f, 0.f};
    acc = __builtin_amdgcn_mfma_f32_32x32x16_bf16(k0, qf0, acc, 0, 0, 0);
    acc = __builtin_amdgcn_mfma_f32_32x32x16_bf16(k1, qf1, acc, 0, 0, 0);
    acc = __builtin_amdgcn_mfma_f32_32x32x16_bf16(k2, qf2, acc, 0, 0, 0);
    acc = __builtin_amdgcn_mfma_f32_32x32x16_bf16(k3, qf3, acc, 0, 0, 0);

    float m0 = fmaxf(fmaxf(acc[0],  acc[1]),  fmaxf(acc[2],  acc[3]));
    float m1 = fmaxf(fmaxf(acc[4],  acc[5]),  fmaxf(acc[6],  acc[7]));
    float m2 = fmaxf(fmaxf(acc[8],  acc[9]),  fmaxf(acc[10], acc[11]));
    float m3 = fmaxf(fmaxf(acc[12], acc[13]), fmaxf(acc[14], acc[15]));
    smax = fmaxf(smax, fmaxf(fmaxf(m0, m1), fmaxf(m2, m3)));
  }
  sm[ln][qg * 2 + hi] = smax;
  __syncthreads();

  if (t < 32) {
    float rv[8];
    #pragma unroll
    for (int j = 0; j < 8; ++j) rv[j] = NEG_INF;
    #pragma unroll
    for (int s = 0; s < 16; ++s) {
      float x = sm[t][s];
      if (x > rv[7]) insert8v(rv, x);
    }
    tau[t] = rv[7];
  }
  __syncthreads();

  // ---- Pass 2: recompute + compact candidates >= tau + rest of zeros ------
  const float tl = tau[ln];
  for (int t16 = 0; t16 < 16; ++t16) {
    const ushort* tb = ktile + (size_t)t16 * 2048;
    bf16x8 k0 = *reinterpret_cast<const bf16x8*>(tb +        kg * 8);
    bf16x8 k1 = *reinterpret_cast<const bf16x8*>(tb +  512 + kg * 8);
    bf16x8 k2 = *reinterpret_cast<const bf16x8*>(tb + 1024 + kg * 8);
    bf16x8 k3 = *reinterpret_cast<const bf16x8*>(tb + 1536 + kg * 8);

    *reinterpret_cast<v4f*>(obase + (size_t)(32 + t16 * 2)     * 2048 + t * 4) = z;
    *reinterpret_cast<v4f*>(obase + (size_t)(32 + t16 * 2 + 1) * 2048 + t * 4) = z;

    f32x16 acc = {0.f, 0.f, 0.f, 0.f, 0.f, 0.f, 0.f, 0.f,
                  0.f, 0.f, 0.f, 0.f, 0.f, 0.f, 0.f, 0.f};
    acc = __builtin_amdgcn_mfma_f32_32x32x16_bf16(k0, qf0, acc, 0, 0, 0);
    acc = __builtin_amdgcn_mfma_f32_32x32x16_bf16(k1, qf1, acc, 0, 0, 0);
    acc = __builtin_amdgcn_mfma_f32_32x32x16_bf16(k2, qf2, acc, 0, 0, 0);
    acc = __builtin_amdgcn_mfma_f32_32x32x16_bf16(k3, qf3, acc, 0, 0, 0);

    const int kb0 = qg * 512 + t16 * 32 + 4 * hi;
#define CHK(r) { float x_ = acc[r]; \
                 if (x_ >= tl) { \
                   int p_ = atomicAdd(&cnt[ln], 1); \
                   if (p_ < CAP) cand[ln][p_] = kb0 + ((r) & 3) + 8 * ((r) >> 2); } }
    CHK(0)  CHK(1)  CHK(2)  CHK(3)
    CHK(4)  CHK(5)  CHK(6)  CHK(7)
    CHK(8)  CHK(9)  CHK(10) CHK(11)
    CHK(12) CHK(13) CHK(14) CHK(15)
#undef CHK
  }
  __syncthreads();   // drains all zero stores (per-wave vmcnt(0) + barrier)

  // ---- exact f32 rescore (bit-identical blocked order) --------------------
  {
    int row = t >> 4, j0 = t & 15;
    int n = min(cnt[row], CAP);
    for (int jj = j0; jj < n; jj += 16) {
      int idx = cand[row][jj];
      const float* kcol = kh + ((size_t)b * NK + idx) * INNER;
      float acc = 0.f;
      #pragma unroll
      for (int dd = 0; dd < INNER; dd += 4) {
        v4f kv = *reinterpret_cast<const v4f*>(kcol + dd);
        v4f qv = *reinterpret_cast<const v4f*>(&qhf[row][dd]);
        float bs = qv[0] * kv[0];
        bs = fmaf(qv[1], kv[1], bs);
        bs = fmaf(qv[2], kv[2], bs);
        bs = fmaf(qv[3], kv[3], bs);
        acc += bs;
      }
      exactv[row][jj] = acc;
    }
  }
  __syncthreads();

  // ---- top-5 of exact scores + softmax ------------------------------------
  if (t < 32) {
    int n = min(cnt[t], CAP);
    float rv[5]; int ri[5];
    #pragma unroll
    for (int j = 0; j < 5; ++j) { rv[j] = NEG_INF; ri[j] = 0; }
    for (int j = 0; j < n; ++j) {
      float x = exactv[t][j];
      if (x > rv[4]) insert5(rv, ri, x, cand[t][j]);
    }
    bool inc4 = (rv[4] >= rv[3]);
    float e1 = expf(rv[1] - rv[0]);
    float e2 = expf(rv[2] - rv[0]);
    float e3 = expf(rv[3] - rv[0]);
    float e4 = inc4 ? expf(rv[4] - rv[0]) : 0.0f;
    float inv = 1.0f / (1.0f + e1 + e2 + e3 + e4);
    w5[t][0] = inv;      w5[t][1] = e1 * inv;  w5[t][2] = e2 * inv;
    w5[t][3] = e3 * inv; w5[t][4] = e4 * inv;
    #pragma unroll
    for (int j = 0; j < 5; ++j) id5[t][j] = ri[j];
    id5[t][5] = inc4 ? 5 : 4;
  }
  __syncthreads();

  // ---- scattered weight stores (zeros already drained) --------------------
  if (t < 160) {
    int row = t / 5, j = t % 5;
    if (j < id5[row][5])
      obase[(size_t)row * NK + id5[row][j]] = w5[row][j];
  }
}

extern "C" void kernel_launch(void* const* d_in, const int* in_sizes, int n_in,
                              void* d_out, int out_size, void* d_ws, size_t ws_size,
                              hipStream_t stream) {
  const float* q  = (const float*)d_in[0];
  const float* k  = (const float*)d_in[1];
  const float* Wq = (const float*)d_in[3];
  const float* Wk = (const float*)d_in[4];

  const size_t NE = (size_t)BATCH * NQ * INNER;     // 1,048,576 per array
  float*  qh  = (float*)d_ws;                       // 4 MB
  float*  kh  = qh + NE;                            // 4 MB
  ushort* qhb = (ushort*)(kh + NE);                 // 2 MB
  ushort* khb = qhb + NE;                           // 2 MB (fragment-major)

  proj_kernel<<<1024, 256, 0, stream>>>(q, k, Wq, Wk, qh, kh, qhb, khb);
  filter_kernel<<<512, 512, 0, stream>>>(qhb, khb, qh, kh, (float*)d_out);
}